// Round 8
// baseline (222.865 us; speedup 1.0000x reference)
//
#include <hip/hip_runtime.h>
#include <math.h>

#define BS 4
#define C 4
#define N 2048
#define D 16
#define KNN 32
#define M 64

typedef unsigned long long u64;
typedef unsigned int u32;

// ---------------------------------------------------------------------------
// Kernel 1: exact 32-NN (sorted ascending, ties -> lower index) per (b,c,n).
// One wave per row; 8 rows (same b,c) per 512-thread block.
// Build per-lane sorted head-5 of u64 keys (dist-bits, idx). Then:
//   pivot p = 33rd-smallest of the 64 lane-minima (bitonic sort of h0);
//   if no lane saturated below p and count(<=p) <= 64:
//       ballot-prefix compact survivors to LDS, one 64-lane bitonic sort,
//       lanes 1..32 emit results (rank 0 dropped = reference top-(k+1)).
//   else: exact serial DPP-extraction fallback (rare, ~1-2% of rows).
// Distance arithmetic replicates numpy f32 semantics bit-exactly.
// ---------------------------------------------------------------------------

__device__ __forceinline__ u32 umin_u32(u32 a, u32 b) { return a < b ? a : b; }

#define DPP_MIN_STAGE(v, ctrl)                                                  \
    v = umin_u32(v, (u32)__builtin_amdgcn_update_dpp(                           \
                        (int)0xFFFFFFFF, (int)(v), (ctrl), 0xF, 0xF, false))

__device__ __forceinline__ u32 wave_min_dpp(u32 v) {
    DPP_MIN_STAGE(v, 0x111);  // row_shr:1
    DPP_MIN_STAGE(v, 0x112);  // row_shr:2
    DPP_MIN_STAGE(v, 0x114);  // row_shr:4
    DPP_MIN_STAGE(v, 0x118);  // row_shr:8
    DPP_MIN_STAGE(v, 0x142);  // row_bcast:15
    DPP_MIN_STAGE(v, 0x143);  // row_bcast:31 -> lane63 = wave min
    return (u32)__builtin_amdgcn_readlane((int)v, 63);
}

__device__ __forceinline__ u64 shfl_xor_u64(u64 v, int m) {
    int lo = __shfl_xor((int)(u32)v, m);
    int hi = __shfl_xor((int)(u32)(v >> 32), m);
    return ((u64)(u32)hi << 32) | (u32)lo;
}

// full ascending bitonic sort of the 64 lanes' values (u64 keys)
__device__ __forceinline__ u64 bitonic64(u64 val, int lane) {
#pragma unroll
    for (int k = 2; k <= 64; k <<= 1) {
#pragma unroll
        for (int j = k >> 1; j > 0; j >>= 1) {
            u64 other = shfl_xor_u64(val, j);
            bool keepmin = (((lane & k) == 0) == ((lane & j) == 0));
            bool take = ((other < val) == keepmin);
            val = take ? other : val;
        }
    }
    return val;
}

__device__ __forceinline__ u32 mbcnt64(u64 m) {
    return __builtin_amdgcn_mbcnt_hi((u32)(m >> 32),
                                     __builtin_amdgcn_mbcnt_lo((u32)m, 0));
}

__device__ __forceinline__ float np_quad(float x, float y, float z) {
#pragma clang fp contract(off)
    float q = (x * x + y * y) + z * z;
    return q;
}

__device__ __forceinline__ float np_dist(const float4& me, const float4& p) {
#pragma clang fp contract(off)
    float inner = (me.x * p.x + me.y * p.y) + me.z * p.z;
    float dist  = ((-2.0f * inner) + p.w) + me.w;
    return dist;
}

__device__ __forceinline__ u64 dist_key(float dist, int j) {
    u32 b = __float_as_uint(dist);
    u32 f = b ^ (0x80000000u | (u32)((int)b >> 31));
    return ((u64)f << 32) | (u32)j;
}

#define INSERT5(x)                                                                     \
    { bool c_ = x < h0; u64 mn_ = c_ ? x : h0, mx_ = c_ ? h0 : x; h0 = mn_; x = mx_; } \
    { bool c_ = x < h1; u64 mn_ = c_ ? x : h1, mx_ = c_ ? h1 : x; h1 = mn_; x = mx_; } \
    { bool c_ = x < h2; u64 mn_ = c_ ? x : h2, mx_ = c_ ? h2 : x; h2 = mn_; x = mx_; } \
    { bool c_ = x < h3; u64 mn_ = c_ ? x : h3, mx_ = c_ ? h3 : x; h3 = mn_; x = mx_; } \
    h4 = (x < h4) ? x : h4;

__global__ __launch_bounds__(512) void knn_kernel(const float* __restrict__ pos,
                                                  int* __restrict__ edge_ws,
                                                  float* __restrict__ dist_ws) {
    __shared__ float4 sp[N];          // {x,y,z,quad} -> 32 KB
    __shared__ u64 slots[8][64];      // per-wave compaction/result buffer, 4 KB
    const int tid  = threadIdx.x;
    const int lane = tid & 63;
    const int wave = tid >> 6;         // 0..7
    const int row0 = blockIdx.x * 8;   // 8 consecutive rows, same (b,c)
    const int bc   = row0 >> 11;

    const float* posr = pos + (size_t)bc * (N * 3);
    for (int j = tid; j < N; j += 512) {
        float x = posr[3 * j], y = posr[3 * j + 1], z = posr[3 * j + 2];
        sp[j] = make_float4(x, y, z, np_quad(x, y, z));
    }
    __syncthreads();

    const int row = row0 + wave;
    const int n   = row & (N - 1);
    const float4 me = sp[n];   // me.w = quad_n

    const u64 SENT = ~0ull;
    u64 h0 = SENT, h1 = SENT, h2 = SENT, h3 = SENT, h4 = SENT;

    // ---- build: stream candidates (self included; rank 0 dropped later) ----
#pragma unroll
    for (int jj = 0; jj < 32; ++jj) {
        int j = jj * 64 + lane;
        float4 p = sp[j];
        u64 x = dist_key(np_dist(me, p), j);
        INSERT5(x)
    }

    // ---- pivot: p = 33rd smallest of the 64 lane-minima ----
    u64 srt = bitonic64(h0, lane);
    u32 plo = (u32)__builtin_amdgcn_readlane((int)(u32)srt, 32);
    u32 phi = (u32)__builtin_amdgcn_readlane((int)(u32)(srt >> 32), 32);
    u64 p = ((u64)phi << 32) | plo;

    u64 m0 = __ballot(h0 <= p);
    u64 m1 = __ballot(h1 <= p);
    u64 m2 = __ballot(h2 <= p);
    u64 m3 = __ballot(h3 <= p);
    u64 m4 = __ballot(h4 <= p);
    int cnt = __popcll(m0) + __popcll(m1) + __popcll(m2) + __popcll(m3) + __popcll(m4);

    u64 v;
    if (m4 == 0ull && cnt <= 64) {
        // ---- fast path: compact survivors, one bitonic sort ----
        slots[wave][lane] = SENT;
        u32 P0 = (u32)__popcll(m0);
        u32 P1 = P0 + (u32)__popcll(m1);
        u32 P2 = P1 + (u32)__popcll(m2);
        if (h0 <= p) slots[wave][mbcnt64(m0)] = h0;
        if (h1 <= p) slots[wave][P0 + mbcnt64(m1)] = h1;
        if (h2 <= p) slots[wave][P1 + mbcnt64(m2)] = h2;
        if (h3 <= p) slots[wave][P2 + mbcnt64(m3)] = h3;
        v = slots[wave][lane];
        v = bitonic64(v, lane);
    } else {
        // ---- exact serial fallback (rare): 33 DPP-extraction rounds ----
        int pc = 0;
        u64 thr = 0ull;
        for (int s = 0; s < KNN + 1; ++s) {
            u32 hd = (u32)(h0 >> 32);
            u32 rd = wave_min_dpp(hd);
            u64 tb = __ballot(hd == rd);
            u32 rl;
            if (__popcll(tb) == 1) {
                int w = (int)(__ffsll((long long)tb) - 1);
                rl = (u32)__builtin_amdgcn_readlane((int)(u32)h0, w);
            } else {
                u32 lo2 = (hd == rd) ? (u32)h0 : 0xFFFFFFFFu;
                rl = wave_min_dpp(lo2);
            }
            bool mine = (hd == rd) && ((u32)h0 == rl);
            if (mine) {
                slots[wave][s] = h0;
                thr = h0;
                h0 = h1; h1 = h2; h2 = h3; h3 = h4; h4 = SENT;
                ++pc;
            }
            if (pc == 5) {
                h0 = SENT; h1 = SENT; h2 = SENT; h3 = SENT; h4 = SENT;
#pragma unroll
                for (int jj = 0; jj < 32; ++jj) {
                    int j = jj * 64 + lane;
                    float4 pp = sp[j];
                    u64 x = dist_key(np_dist(me, pp), j);
                    if (x <= thr) x = SENT;
                    INSERT5(x)
                }
                pc = 0;
            }
        }
        v = slots[wave][lane];
    }

    // ---- emit: lanes 1..32 hold ranks 1..32 (rank 0 = dropped top-1) ----
    if (lane >= 1 && lane <= KNN) {
        u32 fk = (u32)(v >> 32);
        u32 bb = (fk & 0x80000000u) ? (fk ^ 0x80000000u) : ~fk;
        edge_ws[(size_t)row * KNN + lane - 1] = (int)(u32)v;
        dist_ws[(size_t)row * KNN + lane - 1] = __uint_as_float(bb);
    }
}

// ---------------------------------------------------------------------------
// Kernel 2: angle features + gate + gated aggregation + two 128->64 matvecs.
// One wave per (b,n); 8 consecutive n (same b) per 512-thread block.
// aw kept in natural [m][f] layout, stride 129 -> conflict-free write & read.
// ---------------------------------------------------------------------------
__global__ __launch_bounds__(512) void conv_kernel(
    const float* __restrict__ pos, const float* __restrict__ node_fea,
    const float* __restrict__ node_mask, const float* __restrict__ aw,
    const float* __restrict__ sw, const float* __restrict__ w1,
    const float* __restrict__ w2, const int* __restrict__ edge_ws,
    const float* __restrict__ dist_ws, float* __restrict__ out) {
    __shared__ float aw_s[64 * 129];       // aw[m][f] padded: ~33 KB
    __shared__ float theta_lds[8][128];    // [wave][kk*4+cc]
    __shared__ float gate_lds[8][128];     // [wave][cc*32+kk]
    __shared__ int   edge_lds[8][128];     // [wave][cc*32+kk]
    __shared__ float h_lds[8][128];        // [wave][cc*32+dd]
    __shared__ float gsum_lds[8][4];       // [wave][cc]
    __shared__ float outv[8][65];          // [n-offset][m], padded

    const int tid  = threadIdx.x;
    const int lane = tid & 63;
    const int wave = tid >> 6;             // 0..7

    // stage angle_weight, natural layout, padded stride
    for (int i = tid; i < 64 * 128; i += 512) {
        int m = i >> 7, f = i & 127;
        aw_s[m * 129 + f] = aw[i];
    }

    const int row0 = blockIdx.x * 8;   // (b,n) row base, same b across block
    const int b    = row0 >> 11;
    const int n0   = row0 & (N - 1);
    const int row  = row0 + wave;
    const int n    = row & (N - 1);
    const float mval = node_mask[b * N + n];

    // gate scalar: S = sum_m relu(w1[m]) * w2[m]  (valid since dist > 0)
    float S = 0.f;
    for (int m = 0; m < 64; ++m) S += fmaxf(w1[m], 0.f) * w2[m];

    __syncthreads();

    // ---- Phase A: per (cc,kk) pair: direction, theta, gate ----
#pragma unroll
    for (int it = 0; it < 2; ++it) {
        int p  = it * 64 + lane;
        int cc = p >> 5, kk = p & 31;
        int rowc = (b * C + cc) * N + n;
        int e      = edge_ws[(size_t)rowc * KNN + kk];
        float dist = dist_ws[(size_t)rowc * KNN + kk];
        const float* pp = pos + (size_t)rowc * 3;
        const float* qp = pos + ((size_t)(b * C + cc) * N + e) * 3;
        float dx = qp[0] - pp[0], dy = qp[1] - pp[1], dz = qp[2] - pp[2];
        float nrm = fmaxf(sqrtf(dx * dx + dy * dy + dz * dz), 1e-12f);
        float inv = 1.0f / nrm;
        dx *= inv; dy *= inv; dz *= inv;
        int src = lane & 32;   // lane holding kk==0 for this cc-group
        float n0x = __shfl(dx, src), n0y = __shfl(dy, src), n0z = __shfl(dz, src);
        float cosv = (kk == 0) ? 1.f : (dx * n0x + dy * n0y + dz * n0z);
        theta_lds[wave][kk * 4 + cc] = cosv * mval;

        float g = fmaxf(dist * S, 0.f) * mval;
        float gate = 1.f / (1.f + expf(-g));
        gate_lds[wave][cc * 32 + kk] = gate;
        edge_lds[wave][cc * 32 + kk] = e;
        float gs = gate;
#pragma unroll
        for (int off = 1; off < 32; off <<= 1) gs += __shfl_xor(gs, off);
        if (kk == 0) gsum_lds[wave][cc] = gs;
    }
    __syncthreads();

    // ---- Phase B: h[f] = sum_k gate * fea_cat ----
#pragma unroll
    for (int it = 0; it < 2; ++it) {
        int f  = it * 64 + lane;
        int cc = f >> 5, dd = f & 31;
        float h;
        if (dd < 16) {
            float own = node_fea[((size_t)(b * C + cc) * N + n) * D + dd];
            h = own * mval * gsum_lds[wave][cc];
        } else {
            int dd2 = dd - 16;
            const float* nf = node_fea + (size_t)(b * C + cc) * N * D;
            float acc = 0.f;
#pragma unroll 8
            for (int k = 0; k < 32; ++k) {
                int e = edge_lds[wave][cc * 32 + k];
                acc += gate_lds[wave][cc * 32 + k] * nf[e * D + dd2];
            }
            h = acc * mval;
        }
        h_lds[wave][f] = h;
    }
    __syncthreads();

    // ---- Phase C: m = lane; two 128->64 matvecs + epilogue ----
    float fs = 0.f, fe = 0.f;
#pragma unroll 8
    for (int f = 0; f < 128; ++f) {
        fs += aw_s[lane * 129 + f] * theta_lds[wave][f];
        fe += h_lds[wave][f] * sw[f * 64 + lane];
    }
    float v = fs + fe;
    v = (v > 0.f) ? v : 0.01f * v;
    outv[wave][lane] = v * mval;
    __syncthreads();

    // store: thread t -> m = t>>3, n-offset j = t&7
    {
        int m = tid >> 3, j = tid & 7;
        out[((size_t)(b * 64 + m)) * N + n0 + j] = outv[j][m];
    }
}

// ---------------------------------------------------------------------------
extern "C" void kernel_launch(void* const* d_in, const int* in_sizes, int n_in,
                              void* d_out, int out_size, void* d_ws, size_t ws_size,
                              hipStream_t stream) {
    const float* pos       = (const float*)d_in[0];
    const float* node_fea  = (const float*)d_in[1];
    const float* node_mask = (const float*)d_in[2];
    const float* aw        = (const float*)d_in[3];
    const float* sw        = (const float*)d_in[4];
    const float* w1        = (const float*)d_in[5];
    const float* w2        = (const float*)d_in[6];
    float* out = (float*)d_out;

    int*   edge_ws = (int*)d_ws;
    float* dist_ws = (float*)((char*)d_ws + (size_t)BS * C * N * KNN * sizeof(int));

    knn_kernel<<<BS * C * N / 8, 512, 0, stream>>>(pos, edge_ws, dist_ws);
    conv_kernel<<<BS * N / 8, 512, 0, stream>>>(pos, node_fea, node_mask, aw, sw,
                                                w1, w2, edge_ws, dist_ws, out);
}

// Round 9
// 207.226 us; speedup vs baseline: 1.0755x; 1.0755x over previous
//
#include <hip/hip_runtime.h>
#include <math.h>

#define BS 4
#define C 4
#define N 2048
#define D 16
#define KNN 32
#define M 64

typedef unsigned long long u64;
typedef unsigned int u32;

// ---------------------------------------------------------------------------
// Kernel 1: exact 32-NN (sorted ascending, ties -> lower index) per (b,c,n).
// One wave per row; 8 rows (same b,c) per 512-thread block.
// Build per-lane sorted head-5 of u64 keys. Pivot pd = 33rd-smallest h0
// dist-bits (u32 bitonic). Fast path: ballot-compact survivors (distbits<=pd)
// to LDS, per-lane rank via 64 broadcast ds_read_b64 (no cross-lane chains),
// lanes rank 1..32 store directly to global (rank 0 dropped = reference
// top-(k+1) semantics). Exact serial DPP fallback for rare overflow rows.
// Distance arithmetic replicates numpy f32 semantics bit-exactly.
// ---------------------------------------------------------------------------

__device__ __forceinline__ u32 umin_u32(u32 a, u32 b) { return a < b ? a : b; }

#define DPP_MIN_STAGE(v, ctrl)                                                  \
    v = umin_u32(v, (u32)__builtin_amdgcn_update_dpp(                           \
                        (int)0xFFFFFFFF, (int)(v), (ctrl), 0xF, 0xF, false))

__device__ __forceinline__ u32 wave_min_dpp(u32 v) {
    DPP_MIN_STAGE(v, 0x111);  // row_shr:1
    DPP_MIN_STAGE(v, 0x112);  // row_shr:2
    DPP_MIN_STAGE(v, 0x114);  // row_shr:4
    DPP_MIN_STAGE(v, 0x118);  // row_shr:8
    DPP_MIN_STAGE(v, 0x142);  // row_bcast:15
    DPP_MIN_STAGE(v, 0x143);  // row_bcast:31 -> lane63 = wave min
    return (u32)__builtin_amdgcn_readlane((int)v, 63);
}

#define DPP_ADD_STAGE(v, ctrl)                                                  \
    v += __int_as_float(__builtin_amdgcn_update_dpp(                            \
        0, __float_as_int(v), (ctrl), 0xF, 0xF, false))

__device__ __forceinline__ float wave_sum_dpp(float v) {
    DPP_ADD_STAGE(v, 0x111);
    DPP_ADD_STAGE(v, 0x112);
    DPP_ADD_STAGE(v, 0x114);
    DPP_ADD_STAGE(v, 0x118);
    DPP_ADD_STAGE(v, 0x142);
    DPP_ADD_STAGE(v, 0x143);
    return __int_as_float(__builtin_amdgcn_readlane(__float_as_int(v), 63));
}

// ascending bitonic sort of the 64 lanes' u32 values (validated in R8 as u64)
__device__ __forceinline__ u32 bitonic64_u32(u32 val, int lane) {
#pragma unroll
    for (int k = 2; k <= 64; k <<= 1) {
#pragma unroll
        for (int j = k >> 1; j > 0; j >>= 1) {
            u32 other = (u32)__shfl_xor((int)val, j);
            bool keepmin = (((lane & k) == 0) == ((lane & j) == 0));
            bool take = ((other < val) == keepmin);
            val = take ? other : val;
        }
    }
    return val;
}

__device__ __forceinline__ u32 mbcnt64(u64 m) {
    return __builtin_amdgcn_mbcnt_hi((u32)(m >> 32),
                                     __builtin_amdgcn_mbcnt_lo((u32)m, 0));
}

__device__ __forceinline__ float np_quad(float x, float y, float z) {
#pragma clang fp contract(off)
    float q = (x * x + y * y) + z * z;
    return q;
}

__device__ __forceinline__ float np_dist(const float4& me, const float4& p) {
#pragma clang fp contract(off)
    float inner = (me.x * p.x + me.y * p.y) + me.z * p.z;
    float dist  = ((-2.0f * inner) + p.w) + me.w;
    return dist;
}

__device__ __forceinline__ u64 dist_key(float dist, int j) {
    u32 b = __float_as_uint(dist);
    u32 f = b ^ (0x80000000u | (u32)((int)b >> 31));
    return ((u64)f << 32) | (u32)j;
}

#define INSERT5(x)                                                                     \
    { bool c_ = x < h0; u64 mn_ = c_ ? x : h0, mx_ = c_ ? h0 : x; h0 = mn_; x = mx_; } \
    { bool c_ = x < h1; u64 mn_ = c_ ? x : h1, mx_ = c_ ? h1 : x; h1 = mn_; x = mx_; } \
    { bool c_ = x < h2; u64 mn_ = c_ ? x : h2, mx_ = c_ ? h2 : x; h2 = mn_; x = mx_; } \
    { bool c_ = x < h3; u64 mn_ = c_ ? x : h3, mx_ = c_ ? h3 : x; h3 = mn_; x = mx_; } \
    h4 = (x < h4) ? x : h4;

__global__ __launch_bounds__(512) void knn_kernel(const float* __restrict__ pos,
                                                  int* __restrict__ edge_ws,
                                                  float* __restrict__ dist_ws) {
    __shared__ float4 sp[N];          // {x,y,z,quad} -> 32 KB
    __shared__ u64 slots[8][64];      // per-wave compaction buffer, 4 KB
    const int tid  = threadIdx.x;
    const int lane = tid & 63;
    const int wave = tid >> 6;         // 0..7
    const int row0 = blockIdx.x * 8;   // 8 consecutive rows, same (b,c)
    const int bc   = row0 >> 11;

    const float* posr = pos + (size_t)bc * (N * 3);
    for (int j = tid; j < N; j += 512) {
        float x = posr[3 * j], y = posr[3 * j + 1], z = posr[3 * j + 2];
        sp[j] = make_float4(x, y, z, np_quad(x, y, z));
    }
    __syncthreads();

    const int row = row0 + wave;
    const int n   = row & (N - 1);
    const float4 me = sp[n];   // me.w = quad_n

    const u64 SENT = ~0ull;
    u64 h0 = SENT, h1 = SENT, h2 = SENT, h3 = SENT, h4 = SENT;

    // ---- build: stream candidates (self included; rank 0 dropped later) ----
#pragma unroll
    for (int jj = 0; jj < 32; ++jj) {
        int j = jj * 64 + lane;
        float4 p = sp[j];
        u64 x = dist_key(np_dist(me, p), j);
        INSERT5(x)
    }

    // ---- pivot: pd = 33rd-smallest dist-bits among the 64 lane minima ----
    u32 sd = bitonic64_u32((u32)(h0 >> 32), lane);
    u32 pd = (u32)__builtin_amdgcn_readlane((int)sd, 32);

    u64 m0 = __ballot((u32)(h0 >> 32) <= pd);
    u64 m1 = __ballot((u32)(h1 >> 32) <= pd);
    u64 m2 = __ballot((u32)(h2 >> 32) <= pd);
    u64 m3 = __ballot((u32)(h3 >> 32) <= pd);
    u64 m4 = __ballot((u32)(h4 >> 32) <= pd);
    int cnt = __popcll(m0) + __popcll(m1) + __popcll(m2) + __popcll(m3);

    if (m4 == 0ull && cnt <= 64) {
        // ---- fast path: compact survivors; rank-sort via broadcast reads ----
        // unique pad keys, larger than any real key (real high word < 0xFFFFFFFF)
        slots[wave][lane] = (0xFFFFFFFFull << 32) | (u32)(4096 + lane);
        u32 P0 = (u32)__popcll(m0);
        u32 P1 = P0 + (u32)__popcll(m1);
        u32 P2 = P1 + (u32)__popcll(m2);
        if ((u32)(h0 >> 32) <= pd) slots[wave][mbcnt64(m0)] = h0;
        if ((u32)(h1 >> 32) <= pd) slots[wave][P0 + mbcnt64(m1)] = h1;
        if ((u32)(h2 >> 32) <= pd) slots[wave][P1 + mbcnt64(m2)] = h2;
        if ((u32)(h3 >> 32) <= pd) slots[wave][P2 + mbcnt64(m3)] = h3;

        u64 own = slots[wave][lane];
        int rank = 0;
#pragma unroll 16
        for (int i = 0; i < 64; ++i)
            rank += (slots[wave][i] < own) ? 1 : 0;

        if (rank >= 1 && rank <= KNN) {
            u32 fk = (u32)(own >> 32);
            u32 bb = (fk & 0x80000000u) ? (fk ^ 0x80000000u) : ~fk;
            edge_ws[(size_t)row * KNN + rank - 1] = (int)(u32)own;
            dist_ws[(size_t)row * KNN + rank - 1] = __uint_as_float(bb);
        }
    } else {
        // ---- exact serial fallback (rare): 33 DPP-extraction rounds ----
        int pc = 0;
        u64 thr = 0ull;
        for (int s = 0; s < KNN + 1; ++s) {
            u32 hd = (u32)(h0 >> 32);
            u32 rd = wave_min_dpp(hd);
            u64 tb = __ballot(hd == rd);
            u32 rl;
            if (__popcll(tb) == 1) {
                int w = (int)(__ffsll((long long)tb) - 1);
                rl = (u32)__builtin_amdgcn_readlane((int)(u32)h0, w);
            } else {
                u32 lo2 = (hd == rd) ? (u32)h0 : 0xFFFFFFFFu;
                rl = wave_min_dpp(lo2);
            }
            bool mine = (hd == rd) && ((u32)h0 == rl);
            if (mine) {
                slots[wave][s] = h0;
                thr = h0;
                h0 = h1; h1 = h2; h2 = h3; h3 = h4; h4 = SENT;
                ++pc;
            }
            if (pc == 5) {
                h0 = SENT; h1 = SENT; h2 = SENT; h3 = SENT; h4 = SENT;
#pragma unroll
                for (int jj = 0; jj < 32; ++jj) {
                    int j = jj * 64 + lane;
                    float4 pp = sp[j];
                    u64 x = dist_key(np_dist(me, pp), j);
                    if (x <= thr) x = SENT;
                    INSERT5(x)
                }
                pc = 0;
            }
        }
        if (lane >= 1 && lane <= KNN) {
            u64 v = slots[wave][lane];
            u32 fk = (u32)(v >> 32);
            u32 bb = (fk & 0x80000000u) ? (fk ^ 0x80000000u) : ~fk;
            edge_ws[(size_t)row * KNN + lane - 1] = (int)(u32)v;
            dist_ws[(size_t)row * KNN + lane - 1] = __uint_as_float(bb);
        }
    }
}

// ---------------------------------------------------------------------------
// Kernel 2: angle features + gate + gated aggregation + two 128->64 matvecs.
// One wave per (b,n); 8 consecutive n (same b) per 512-thread block.
// aw kept in natural [m][f] layout, stride 129 -> conflict-free write & read.
// ---------------------------------------------------------------------------
__global__ __launch_bounds__(512) void conv_kernel(
    const float* __restrict__ pos, const float* __restrict__ node_fea,
    const float* __restrict__ node_mask, const float* __restrict__ aw,
    const float* __restrict__ sw, const float* __restrict__ w1,
    const float* __restrict__ w2, const int* __restrict__ edge_ws,
    const float* __restrict__ dist_ws, float* __restrict__ out) {
    __shared__ float aw_s[64 * 129];       // aw[m][f] padded: ~33 KB
    __shared__ float theta_lds[8][128];    // [wave][kk*4+cc]
    __shared__ float gate_lds[8][128];     // [wave][cc*32+kk]
    __shared__ int   edge_lds[8][128];     // [wave][cc*32+kk]
    __shared__ float h_lds[8][128];        // [wave][cc*32+dd]
    __shared__ float gsum_lds[8][4];       // [wave][cc]
    __shared__ float outv[8][65];          // [n-offset][m], padded

    const int tid  = threadIdx.x;
    const int lane = tid & 63;
    const int wave = tid >> 6;             // 0..7

    // stage angle_weight, natural layout, padded stride
    for (int i = tid; i < 64 * 128; i += 512) {
        int m = i >> 7, f = i & 127;
        aw_s[m * 129 + f] = aw[i];
    }

    const int row0 = blockIdx.x * 8;   // (b,n) row base, same b across block
    const int b    = row0 >> 11;
    const int n0   = row0 & (N - 1);
    const int row  = row0 + wave;
    const int n    = row & (N - 1);
    const float mval = node_mask[b * N + n];

    // gate scalar S = sum_m relu(w1[m]) * w2[m]: one lane-parallel DPP sum
    float S = wave_sum_dpp(fmaxf(w1[lane], 0.f) * w2[lane]);

    __syncthreads();

    // ---- Phase A: per (cc,kk) pair: direction, theta, gate ----
#pragma unroll
    for (int it = 0; it < 2; ++it) {
        int p  = it * 64 + lane;
        int cc = p >> 5, kk = p & 31;
        int rowc = (b * C + cc) * N + n;
        int e      = edge_ws[(size_t)rowc * KNN + kk];
        float dist = dist_ws[(size_t)rowc * KNN + kk];
        const float* pp = pos + (size_t)rowc * 3;
        const float* qp = pos + ((size_t)(b * C + cc) * N + e) * 3;
        float dx = qp[0] - pp[0], dy = qp[1] - pp[1], dz = qp[2] - pp[2];
        float nrm = fmaxf(sqrtf(dx * dx + dy * dy + dz * dz), 1e-12f);
        float inv = 1.0f / nrm;
        dx *= inv; dy *= inv; dz *= inv;
        int src = lane & 32;   // lane holding kk==0 for this cc-group
        float n0x = __shfl(dx, src), n0y = __shfl(dy, src), n0z = __shfl(dz, src);
        float cosv = (kk == 0) ? 1.f : (dx * n0x + dy * n0y + dz * n0z);
        theta_lds[wave][kk * 4 + cc] = cosv * mval;

        float g = fmaxf(dist * S, 0.f) * mval;
        float gate = 1.f / (1.f + expf(-g));
        gate_lds[wave][cc * 32 + kk] = gate;
        edge_lds[wave][cc * 32 + kk] = e;
        float gs = gate;
#pragma unroll
        for (int off = 1; off < 32; off <<= 1) gs += __shfl_xor(gs, off);
        if (kk == 0) gsum_lds[wave][cc] = gs;
    }
    __syncthreads();

    // ---- Phase B: h[f] = sum_k gate * fea_cat ----
#pragma unroll
    for (int it = 0; it < 2; ++it) {
        int f  = it * 64 + lane;
        int cc = f >> 5, dd = f & 31;
        float h;
        if (dd < 16) {
            float own = node_fea[((size_t)(b * C + cc) * N + n) * D + dd];
            h = own * mval * gsum_lds[wave][cc];
        } else {
            int dd2 = dd - 16;
            const float* nf = node_fea + (size_t)(b * C + cc) * N * D;
            float acc = 0.f;
#pragma unroll
            for (int k = 0; k < 32; ++k) {
                int e = edge_lds[wave][cc * 32 + k];
                acc += gate_lds[wave][cc * 32 + k] * nf[e * D + dd2];
            }
            h = acc * mval;
        }
        h_lds[wave][f] = h;
    }
    __syncthreads();

    // ---- Phase C: m = lane; two 128->64 matvecs + epilogue ----
    float fs = 0.f, fe = 0.f;
#pragma unroll 8
    for (int f = 0; f < 128; ++f) {
        fs += aw_s[lane * 129 + f] * theta_lds[wave][f];
        fe += h_lds[wave][f] * sw[f * 64 + lane];
    }
    float v = fs + fe;
    v = (v > 0.f) ? v : 0.01f * v;
    outv[wave][lane] = v * mval;
    __syncthreads();

    // store: thread t -> m = t>>3, n-offset j = t&7
    {
        int m = tid >> 3, j = tid & 7;
        out[((size_t)(b * 64 + m)) * N + n0 + j] = outv[j][m];
    }
}

// ---------------------------------------------------------------------------
extern "C" void kernel_launch(void* const* d_in, const int* in_sizes, int n_in,
                              void* d_out, int out_size, void* d_ws, size_t ws_size,
                              hipStream_t stream) {
    const float* pos       = (const float*)d_in[0];
    const float* node_fea  = (const float*)d_in[1];
    const float* node_mask = (const float*)d_in[2];
    const float* aw        = (const float*)d_in[3];
    const float* sw        = (const float*)d_in[4];
    const float* w1        = (const float*)d_in[5];
    const float* w2        = (const float*)d_in[6];
    float* out = (float*)d_out;

    int*   edge_ws = (int*)d_ws;
    float* dist_ws = (float*)((char*)d_ws + (size_t)BS * C * N * KNN * sizeof(int));

    knn_kernel<<<BS * C * N / 8, 512, 0, stream>>>(pos, edge_ws, dist_ws);
    conv_kernel<<<BS * N / 8, 512, 0, stream>>>(pos, node_fea, node_mask, aw, sw,
                                                w1, w2, edge_ws, dist_ws, out);
}

// Round 10
// 184.141 us; speedup vs baseline: 1.2103x; 1.1254x over previous
//
#include <hip/hip_runtime.h>
#include <math.h>

#define BS 4
#define C 4
#define N 2048
#define D 16
#define KNN 32
#define M 64

typedef unsigned long long u64;
typedef unsigned int u32;
typedef unsigned short u16;

// ---------------------------------------------------------------------------
// Kernel 1: exact 32-NN (sorted ascending, ties -> lower index) per (b,c,n).
// TWO rows per wave; 16 rows (same b,c) per 512-thread block.
// Pass 1: per-lane min of flipped dist-bits (v_min_u32 only, no sorted heads).
// Pivot pd = 33rd-smallest of the 64 lane minima (u32 bitonic, interleaved
// for both rows). Guarantee: >=33 keys have distbits<=pd, so top-33 survive.
// Pass 2: recompute dists (bit-identical), ballot-prefix compact survivors
// (typ. ~46) into LDS. Rank-sort via broadcast ds_read + u64 compares; ranks
// 1..32 store (rank 0 dropped = reference top-(k+1) semantics).
// Serial DPP fallback only when cnt>128 (~never; exactness guarantee).
// Distance arithmetic replicates numpy f32 semantics bit-exactly:
//   inner = (x*x' + y*y') + z*z'   (sequential, no fma)
//   quad  = (x*x + y*y) + z*z
//   dist  = ((-2*inner) + quad_j) + quad_n
// ---------------------------------------------------------------------------

__device__ __forceinline__ u32 umin_u32(u32 a, u32 b) { return a < b ? a : b; }

#define DPP_MIN_STAGE(v, ctrl)                                                  \
    v = umin_u32(v, (u32)__builtin_amdgcn_update_dpp(                           \
                        (int)0xFFFFFFFF, (int)(v), (ctrl), 0xF, 0xF, false))

__device__ __forceinline__ u32 wave_min_dpp(u32 v) {
    DPP_MIN_STAGE(v, 0x111);
    DPP_MIN_STAGE(v, 0x112);
    DPP_MIN_STAGE(v, 0x114);
    DPP_MIN_STAGE(v, 0x118);
    DPP_MIN_STAGE(v, 0x142);
    DPP_MIN_STAGE(v, 0x143);
    return (u32)__builtin_amdgcn_readlane((int)v, 63);
}

#define DPP_ADD_STAGE(v, ctrl)                                                  \
    v += __int_as_float(__builtin_amdgcn_update_dpp(                            \
        0, __float_as_int(v), (ctrl), 0xF, 0xF, false))

__device__ __forceinline__ float wave_sum_dpp(float v) {
    DPP_ADD_STAGE(v, 0x111);
    DPP_ADD_STAGE(v, 0x112);
    DPP_ADD_STAGE(v, 0x114);
    DPP_ADD_STAGE(v, 0x118);
    DPP_ADD_STAGE(v, 0x142);
    DPP_ADD_STAGE(v, 0x143);
    return __int_as_float(__builtin_amdgcn_readlane(__float_as_int(v), 63));
}

__device__ __forceinline__ u32 mbcnt64(u64 m) {
    return __builtin_amdgcn_mbcnt_hi((u32)(m >> 32),
                                     __builtin_amdgcn_mbcnt_lo((u32)m, 0));
}

__device__ __forceinline__ float np_quad(float x, float y, float z) {
#pragma clang fp contract(off)
    float q = (x * x + y * y) + z * z;
    return q;
}

__device__ __forceinline__ float np_dist(const float4& me, const float4& p) {
#pragma clang fp contract(off)
    float inner = (me.x * p.x + me.y * p.y) + me.z * p.z;
    float dist  = ((-2.0f * inner) + p.w) + me.w;
    return dist;
}

__device__ __forceinline__ u32 flip_bits(float dist) {
    u32 b = __float_as_uint(dist);
    return b ^ (0x80000000u | (u32)((int)b >> 31));
}

__device__ __forceinline__ u64 dist_key(float dist, int j) {
    return ((u64)flip_bits(dist) << 32) | (u32)j;
}

// rank-sort survivors in sl[0..cnt) and emit ranks 1..32
__device__ __forceinline__ void emit_rank(u64* sl, int cnt, int row, int lane,
                                          u16* __restrict__ edge_ws,
                                          float* __restrict__ dist_ws) {
    if (lane < 4) sl[cnt + lane] = ~0ull;   // pads for the unroll-4 overshoot
    u64 own1 = sl[lane];
    if (lane >= cnt) own1 = ~0ull;
    int r1 = 0;
    for (int i = 0; i < cnt; i += 4) {
        u64 s0 = sl[i], s1 = sl[i + 1], s2 = sl[i + 2], s3 = sl[i + 3];
        r1 += (s0 < own1) + (s1 < own1) + (s2 < own1) + (s3 < own1);
    }
    if (r1 >= 1 && r1 <= KNN) {
        u32 fk = (u32)(own1 >> 32);
        u32 bb = (fk & 0x80000000u) ? (fk ^ 0x80000000u) : ~fk;
        edge_ws[(size_t)row * KNN + r1 - 1] = (u16)(u32)own1;
        dist_ws[(size_t)row * KNN + r1 - 1] = __uint_as_float(bb);
    }
    if (cnt > 64) {   // uncommon (~1%), wave-uniform
        u64 own2 = (64 + lane < cnt) ? sl[64 + lane] : ~0ull;
        int r2 = 0;
        for (int i = 0; i < cnt; i += 4) {
            u64 s0 = sl[i], s1 = sl[i + 1], s2 = sl[i + 2], s3 = sl[i + 3];
            r2 += (s0 < own2) + (s1 < own2) + (s2 < own2) + (s3 < own2);
        }
        if (r2 >= 1 && r2 <= KNN) {
            u32 fk = (u32)(own2 >> 32);
            u32 bb = (fk & 0x80000000u) ? (fk ^ 0x80000000u) : ~fk;
            edge_ws[(size_t)row * KNN + r2 - 1] = (u16)(u32)own2;
            dist_ws[(size_t)row * KNN + r2 - 1] = __uint_as_float(bb);
        }
    }
}

#define INSERT5(x)                                                                     \
    { bool c_ = x < h0; u64 mn_ = c_ ? x : h0, mx_ = c_ ? h0 : x; h0 = mn_; x = mx_; } \
    { bool c_ = x < h1; u64 mn_ = c_ ? x : h1, mx_ = c_ ? h1 : x; h1 = mn_; x = mx_; } \
    { bool c_ = x < h2; u64 mn_ = c_ ? x : h2, mx_ = c_ ? h2 : x; h2 = mn_; x = mx_; } \
    { bool c_ = x < h3; u64 mn_ = c_ ? x : h3, mx_ = c_ ? h3 : x; h3 = mn_; x = mx_; } \
    h4 = (x < h4) ? x : h4;

// exact serial fallback for cnt>128 (essentially never executes)
__device__ void serial_row(const float4* sp, float4 me, int row, int lane,
                           u64* sl, u16* __restrict__ edge_ws,
                           float* __restrict__ dist_ws) {
    const u64 SENT = ~0ull;
    u64 h0 = SENT, h1 = SENT, h2 = SENT, h3 = SENT, h4 = SENT;
#pragma unroll
    for (int jj = 0; jj < 32; ++jj) {
        int j = jj * 64 + lane;
        float4 p = sp[j];
        u64 x = dist_key(np_dist(me, p), j);
        INSERT5(x)
    }
    int pc = 0;
    u64 thr = 0ull;
    for (int s = 0; s < KNN + 1; ++s) {
        u32 hd = (u32)(h0 >> 32);
        u32 rd = wave_min_dpp(hd);
        u64 tb = __ballot(hd == rd);
        u32 rl;
        if (__popcll(tb) == 1) {
            int w = (int)(__ffsll((long long)tb) - 1);
            rl = (u32)__builtin_amdgcn_readlane((int)(u32)h0, w);
        } else {
            u32 lo2 = (hd == rd) ? (u32)h0 : 0xFFFFFFFFu;
            rl = wave_min_dpp(lo2);
        }
        bool mine = (hd == rd) && ((u32)h0 == rl);
        if (mine) {
            sl[s] = h0;
            thr = h0;
            h0 = h1; h1 = h2; h2 = h3; h3 = h4; h4 = SENT;
            ++pc;
        }
        if (pc == 5) {
            h0 = SENT; h1 = SENT; h2 = SENT; h3 = SENT; h4 = SENT;
#pragma unroll
            for (int jj = 0; jj < 32; ++jj) {
                int j = jj * 64 + lane;
                float4 pp = sp[j];
                u64 x = dist_key(np_dist(me, pp), j);
                if (x <= thr) x = SENT;
                INSERT5(x)
            }
            pc = 0;
        }
    }
    if (lane >= 1 && lane <= KNN) {
        u64 v = sl[lane];
        u32 fk = (u32)(v >> 32);
        u32 bb = (fk & 0x80000000u) ? (fk ^ 0x80000000u) : ~fk;
        edge_ws[(size_t)row * KNN + lane - 1] = (u16)(u32)v;
        dist_ws[(size_t)row * KNN + lane - 1] = __uint_as_float(bb);
    }
}

__global__ __launch_bounds__(512) void knn_kernel(const float* __restrict__ pos,
                                                  u16* __restrict__ edge_ws,
                                                  float* __restrict__ dist_ws) {
    __shared__ float4 sp[N];          // 32 KB
    __shared__ u64 slots[16][132];    // 16.5 KB (2 rows per wave x 8 waves)
    const int tid  = threadIdx.x;
    const int lane = tid & 63;
    const int wave = tid >> 6;          // 0..7
    const int rb   = blockIdx.x * 16;   // 16 rows per block, same (b,c)
    const int bc   = rb >> 11;

    const float* posr = pos + (size_t)bc * (N * 3);
    for (int j = tid; j < N; j += 512) {
        float x = posr[3 * j], y = posr[3 * j + 1], z = posr[3 * j + 2];
        sp[j] = make_float4(x, y, z, np_quad(x, y, z));
    }
    __syncthreads();

    const int rowA = rb + wave * 2, rowB = rowA + 1;
    const int nA = rowA & (N - 1), nB = nA + 1;
    const float4 meA = sp[nA];
    const float4 meB = sp[nB];

    // ---- pass 1: per-lane min of flipped dist-bits, both rows ----
    u32 mnA = 0xFFFFFFFFu, mnB = 0xFFFFFFFFu;
#pragma unroll
    for (int jj = 0; jj < 32; ++jj) {
        int j = jj * 64 + lane;
        float4 p = sp[j];
        mnA = umin_u32(mnA, flip_bits(np_dist(meA, p)));
        mnB = umin_u32(mnB, flip_bits(np_dist(meB, p)));
    }

    // ---- pivots: 33rd-smallest lane min (interleaved u32 bitonic) ----
    u32 vA = mnA, vB = mnB;
#pragma unroll
    for (int k = 2; k <= 64; k <<= 1) {
#pragma unroll
        for (int j = k >> 1; j > 0; j >>= 1) {
            u32 oA = (u32)__shfl_xor((int)vA, j);
            u32 oB = (u32)__shfl_xor((int)vB, j);
            bool keepmin = (((lane & k) == 0) == ((lane & j) == 0));
            vA = ((oA < vA) == keepmin) ? oA : vA;
            vB = ((oB < vB) == keepmin) ? oB : vB;
        }
    }
    u32 pdA = (u32)__builtin_amdgcn_readlane((int)vA, 32);
    u32 pdB = (u32)__builtin_amdgcn_readlane((int)vB, 32);

    // ---- pass 2: recompute + ballot-prefix compact survivors to LDS ----
    u64* slA = slots[wave * 2];
    u64* slB = slots[wave * 2 + 1];
    u32 baseA = 0, baseB = 0;
#pragma unroll
    for (int jj = 0; jj < 32; ++jj) {
        int j = jj * 64 + lane;
        float4 p = sp[j];
        u32 fA = flip_bits(np_dist(meA, p));
        u32 fB = flip_bits(np_dist(meB, p));
        bool sA = fA <= pdA;
        bool sB = fB <= pdB;
        u64 mA = __ballot(sA);
        u64 mB = __ballot(sB);
        u32 posA = sA ? (baseA + mbcnt64(mA)) : 131u;  // dummy slot for non-survivors
        u32 posB = sB ? (baseB + mbcnt64(mB)) : 131u;
        slA[posA] = ((u64)fA << 32) | (u32)j;
        slB[posB] = ((u64)fB << 32) | (u32)j;
        baseA += (u32)__popcll(mA);
        baseB += (u32)__popcll(mB);
    }
    int cntA = (int)baseA, cntB = (int)baseB;

    if (cntA <= 128) emit_rank(slA, cntA, rowA, lane, edge_ws, dist_ws);
    else             serial_row(sp, meA, rowA, lane, slA, edge_ws, dist_ws);
    if (cntB <= 128) emit_rank(slB, cntB, rowB, lane, edge_ws, dist_ws);
    else             serial_row(sp, meB, rowB, lane, slB, edge_ws, dist_ws);
}

// ---------------------------------------------------------------------------
// Prep: transpose angle_weight [64][128] -> awT [128][64] in workspace.
// ---------------------------------------------------------------------------
__global__ void prep_kernel(const float* __restrict__ aw, float* __restrict__ awT) {
    int i = blockIdx.x * 256 + threadIdx.x;   // 8192
    awT[(i & 127) * 64 + (i >> 7)] = aw[i];
}

// ---------------------------------------------------------------------------
// Kernel 2: angle features + gate + gated aggregation + two 128->64 matvecs.
// One wave per (b,n); 8 consecutive n (same b) per 512-thread block.
// All intermediates wave-private in LDS -> only ONE barrier (outv transpose).
// awT/sw read coalesced from global (L2-resident, 32 KB each).
// ---------------------------------------------------------------------------
__global__ __launch_bounds__(512) void conv_kernel(
    const float* __restrict__ pos, const float* __restrict__ node_fea,
    const float* __restrict__ node_mask, const float* __restrict__ aw_t,
    const float* __restrict__ sw, const float* __restrict__ w1,
    const float* __restrict__ w2, const u16* __restrict__ edge_ws,
    const float* __restrict__ dist_ws, float* __restrict__ out) {
    __shared__ float theta_lds[8][128];    // [wave][kk*4+cc]
    __shared__ float gate_lds[8][128];     // [wave][cc*32+kk]
    __shared__ int   edge_lds[8][128];     // [wave][cc*32+kk]
    __shared__ float h_lds[8][128];        // [wave][cc*32+dd]
    __shared__ float gsum_lds[8][4];       // [wave][cc]
    __shared__ float outv[8][65];          // [n-offset][m], padded

    const int tid  = threadIdx.x;
    const int lane = tid & 63;
    const int wave = tid >> 6;             // 0..7

    const int row0 = blockIdx.x * 8;   // (b,n) row base, same b across block
    const int b    = row0 >> 11;
    const int n0   = row0 & (N - 1);
    const int row  = row0 + wave;
    const int n    = row & (N - 1);
    const float mval = node_mask[b * N + n];

    // gate scalar S = sum_m relu(w1[m]) * w2[m]
    float S = wave_sum_dpp(fmaxf(w1[lane], 0.f) * w2[lane]);

    // ---- Phase A: per (cc,kk) pair: direction, theta, gate (wave-private) ----
#pragma unroll
    for (int it = 0; it < 2; ++it) {
        int p  = it * 64 + lane;
        int cc = p >> 5, kk = p & 31;
        int rowc = (b * C + cc) * N + n;
        int e      = edge_ws[(size_t)rowc * KNN + kk];
        float dist = dist_ws[(size_t)rowc * KNN + kk];
        const float* pp = pos + (size_t)rowc * 3;
        const float* qp = pos + ((size_t)(b * C + cc) * N + e) * 3;
        float dx = qp[0] - pp[0], dy = qp[1] - pp[1], dz = qp[2] - pp[2];
        float nrm = fmaxf(sqrtf(dx * dx + dy * dy + dz * dz), 1e-12f);
        float inv = 1.0f / nrm;
        dx *= inv; dy *= inv; dz *= inv;
        int src = lane & 32;   // lane holding kk==0 for this cc-group
        float n0x = __shfl(dx, src), n0y = __shfl(dy, src), n0z = __shfl(dz, src);
        float cosv = (kk == 0) ? 1.f : (dx * n0x + dy * n0y + dz * n0z);
        theta_lds[wave][kk * 4 + cc] = cosv * mval;

        float g = fmaxf(dist * S, 0.f) * mval;
        float gate = 1.f / (1.f + expf(-g));
        gate_lds[wave][cc * 32 + kk] = gate;
        edge_lds[wave][cc * 32 + kk] = e;
        float gs = gate;
#pragma unroll
        for (int off = 1; off < 32; off <<= 1) gs += __shfl_xor(gs, off);
        if (kk == 0) gsum_lds[wave][cc] = gs;
    }

    // ---- Phase B: h[f] = sum_k gate * fea_cat (wave-private) ----
#pragma unroll
    for (int it = 0; it < 2; ++it) {
        int f  = it * 64 + lane;
        int cc = f >> 5, dd = f & 31;
        float h;
        if (dd < 16) {
            float own = node_fea[((size_t)(b * C + cc) * N + n) * D + dd];
            h = own * mval * gsum_lds[wave][cc];
        } else {
            int dd2 = dd - 16;
            const float* nf = node_fea + (size_t)(b * C + cc) * N * D;
            float acc = 0.f;
#pragma unroll
            for (int k = 0; k < 32; ++k) {
                int e = edge_lds[wave][cc * 32 + k];
                acc += gate_lds[wave][cc * 32 + k] * nf[e * D + dd2];
            }
            h = acc * mval;
        }
        h_lds[wave][f] = h;
    }

    // ---- Phase C: m = lane; two 128->64 matvecs + epilogue ----
    float fs = 0.f, fe = 0.f;
#pragma unroll 8
    for (int f = 0; f < 128; ++f) {
        fs += aw_t[f * 64 + lane] * theta_lds[wave][f];
        fe += h_lds[wave][f] * sw[f * 64 + lane];
    }
    float v = fs + fe;
    v = (v > 0.f) ? v : 0.01f * v;
    outv[wave][lane] = v * mval;
    __syncthreads();   // the only cross-wave handoff (outv transpose)

    // store: thread t -> m = t>>3, n-offset j = t&7
    {
        int m = tid >> 3, j = tid & 7;
        out[((size_t)(b * 64 + m)) * N + n0 + j] = outv[j][m];
    }
}

// ---------------------------------------------------------------------------
extern "C" void kernel_launch(void* const* d_in, const int* in_sizes, int n_in,
                              void* d_out, int out_size, void* d_ws, size_t ws_size,
                              hipStream_t stream) {
    const float* pos       = (const float*)d_in[0];
    const float* node_fea  = (const float*)d_in[1];
    const float* node_mask = (const float*)d_in[2];
    const float* aw        = (const float*)d_in[3];
    const float* sw        = (const float*)d_in[4];
    const float* w1        = (const float*)d_in[5];
    const float* w2        = (const float*)d_in[6];
    float* out = (float*)d_out;

    // ws layout: dist f32 4 MB | edge u16 2 MB | awT 32 KB   (total ~6.03 MB)
    float* dist_ws = (float*)d_ws;
    u16*   edge_ws = (u16*)((char*)d_ws + 4u * 1024 * 1024);
    float* awT     = (float*)((char*)d_ws + 6u * 1024 * 1024);

    prep_kernel<<<32, 256, 0, stream>>>(aw, awT);
    knn_kernel<<<BS * C * N / 16, 512, 0, stream>>>(pos, edge_ws, dist_ws);
    conv_kernel<<<BS * N / 8, 512, 0, stream>>>(pos, node_fea, node_mask, awT, sw,
                                                w1, w2, edge_ws, dist_ws, out);
}

// Round 11
// 178.702 us; speedup vs baseline: 1.2471x; 1.0304x over previous
//
#include <hip/hip_runtime.h>
#include <math.h>

#define BS 4
#define C 4
#define N 2048
#define D 16
#define KNN 32
#define M 64

typedef unsigned long long u64;
typedef unsigned int u32;
typedef unsigned short u16;

// ---------------------------------------------------------------------------
// Kernel 1: exact 32-NN (sorted ascending, ties -> lower index) per (b,c,n).
// TWO rows per wave; 16 rows (same b,c) per 512-thread block.
// Pass 1: per-lane min of flipped dist-bits. Pivot pd = 33rd-smallest of the
// 64 lane minima (u32 bitonic, interleaved for both rows). Guarantee: >=33
// keys have distbits<=pd, so the top-33 always survive.
// Pass 2: recompute dists (bit-identical), EXEC-MASKED ballot-prefix compact
// of survivors (typ. ~46) into LDS (no dummy-slot writes -> no conflicts).
// Rank-sort via broadcast ds_read + u64 compares; ranks 1..32 store (rank 0
// dropped = reference top-(k+1) semantics). Register-light exact rescan
// fallback when cnt>128 (~never).
// Distance arithmetic replicates numpy f32 semantics bit-exactly:
//   inner = (x*x' + y*y') + z*z'   (sequential, no fma)
//   quad  = (x*x + y*y) + z*z
//   dist  = ((-2*inner) + quad_j) + quad_n
// ---------------------------------------------------------------------------

__device__ __forceinline__ u32 umin_u32(u32 a, u32 b) { return a < b ? a : b; }

#define DPP_MIN_STAGE(v, ctrl)                                                  \
    v = umin_u32(v, (u32)__builtin_amdgcn_update_dpp(                           \
                        (int)0xFFFFFFFF, (int)(v), (ctrl), 0xF, 0xF, false))

__device__ __forceinline__ u32 wave_min_dpp(u32 v) {
    DPP_MIN_STAGE(v, 0x111);
    DPP_MIN_STAGE(v, 0x112);
    DPP_MIN_STAGE(v, 0x114);
    DPP_MIN_STAGE(v, 0x118);
    DPP_MIN_STAGE(v, 0x142);
    DPP_MIN_STAGE(v, 0x143);
    return (u32)__builtin_amdgcn_readlane((int)v, 63);
}

#define DPP_ADD_STAGE(v, ctrl)                                                  \
    v += __int_as_float(__builtin_amdgcn_update_dpp(                            \
        0, __float_as_int(v), (ctrl), 0xF, 0xF, false))

__device__ __forceinline__ float wave_sum_dpp(float v) {
    DPP_ADD_STAGE(v, 0x111);
    DPP_ADD_STAGE(v, 0x112);
    DPP_ADD_STAGE(v, 0x114);
    DPP_ADD_STAGE(v, 0x118);
    DPP_ADD_STAGE(v, 0x142);
    DPP_ADD_STAGE(v, 0x143);
    return __int_as_float(__builtin_amdgcn_readlane(__float_as_int(v), 63));
}

__device__ __forceinline__ u32 mbcnt64(u64 m) {
    return __builtin_amdgcn_mbcnt_hi((u32)(m >> 32),
                                     __builtin_amdgcn_mbcnt_lo((u32)m, 0));
}

__device__ __forceinline__ float np_quad(float x, float y, float z) {
#pragma clang fp contract(off)
    float q = (x * x + y * y) + z * z;
    return q;
}

__device__ __forceinline__ float np_dist(const float4& me, const float4& p) {
#pragma clang fp contract(off)
    float inner = (me.x * p.x + me.y * p.y) + me.z * p.z;
    float dist  = ((-2.0f * inner) + p.w) + me.w;
    return dist;
}

__device__ __forceinline__ u32 flip_bits(float dist) {
    u32 b = __float_as_uint(dist);
    return b ^ (0x80000000u | (u32)((int)b >> 31));
}

__device__ __forceinline__ u64 dist_key(float dist, int j) {
    return ((u64)flip_bits(dist) << 32) | (u32)j;
}

// rank-sort survivors in sl[0..cnt) and emit ranks 1..32
__device__ __forceinline__ void emit_rank(u64* sl, int cnt, int row, int lane,
                                          u16* __restrict__ edge_ws,
                                          float* __restrict__ dist_ws) {
    if (lane < 4) sl[cnt + lane] = ~0ull;   // pads for the unroll-4 overshoot
    u64 own1 = sl[lane];
    if (lane >= cnt) own1 = ~0ull;
    int r1 = 0;
    for (int i = 0; i < cnt; i += 4) {
        u64 s0 = sl[i], s1 = sl[i + 1], s2 = sl[i + 2], s3 = sl[i + 3];
        r1 += (s0 < own1) + (s1 < own1) + (s2 < own1) + (s3 < own1);
    }
    if (r1 >= 1 && r1 <= KNN) {
        u32 fk = (u32)(own1 >> 32);
        u32 bb = (fk & 0x80000000u) ? (fk ^ 0x80000000u) : ~fk;
        edge_ws[(size_t)row * KNN + r1 - 1] = (u16)(u32)own1;
        dist_ws[(size_t)row * KNN + r1 - 1] = __uint_as_float(bb);
    }
    if (cnt > 64) {   // uncommon (~1%), wave-uniform
        u64 own2 = (64 + lane < cnt) ? sl[64 + lane] : ~0ull;
        int r2 = 0;
        for (int i = 0; i < cnt; i += 4) {
            u64 s0 = sl[i], s1 = sl[i + 1], s2 = sl[i + 2], s3 = sl[i + 3];
            r2 += (s0 < own2) + (s1 < own2) + (s2 < own2) + (s3 < own2);
        }
        if (r2 >= 1 && r2 <= KNN) {
            u32 fk = (u32)(own2 >> 32);
            u32 bb = (fk & 0x80000000u) ? (fk ^ 0x80000000u) : ~fk;
            edge_ws[(size_t)row * KNN + r2 - 1] = (u16)(u32)own2;
            dist_ws[(size_t)row * KNN + r2 - 1] = __uint_as_float(bb);
        }
    }
}

// register-light exact fallback (cnt>128, ~never): 33 rescan-extract rounds
__device__ __attribute__((noinline)) void slow_row(const float4* sp, float4 me,
                                                   int row, int lane,
                                                   u16* __restrict__ edge_ws,
                                                   float* __restrict__ dist_ws) {
    u64 thr = 0ull;   // all real keys are > 0 (flip==0 would require NaN dist)
    for (int s = 0; s <= KNN; ++s) {
        u64 best = ~0ull;
        for (int jj = 0; jj < 32; ++jj) {
            int j = jj * 64 + lane;
            u64 x = dist_key(np_dist(me, sp[j]), j);
            if (x > thr && x < best) best = x;
        }
        u32 bh = (u32)(best >> 32);
        u32 rh = wave_min_dpp(bh);
        u32 bl = (bh == rh) ? (u32)best : 0xFFFFFFFFu;
        u32 rl = wave_min_dpp(bl);
        thr = ((u64)rh << 32) | rl;
        if (s >= 1 && lane == s - 1) {
            u32 bb = (rh & 0x80000000u) ? (rh ^ 0x80000000u) : ~rh;
            edge_ws[(size_t)row * KNN + s - 1] = (u16)rl;
            dist_ws[(size_t)row * KNN + s - 1] = __uint_as_float(bb);
        }
    }
}

__global__ __launch_bounds__(512) void knn_kernel(const float* __restrict__ pos,
                                                  u16* __restrict__ edge_ws,
                                                  float* __restrict__ dist_ws) {
    __shared__ float4 sp[N];          // 32 KB
    __shared__ u64 slots[16][132];    // 16.5 KB (2 rows per wave x 8 waves)
    const int tid  = threadIdx.x;
    const int lane = tid & 63;
    const int wave = tid >> 6;          // 0..7
    const int rb   = blockIdx.x * 16;   // 16 rows per block, same (b,c)
    const int bc   = rb >> 11;

    const float* posr = pos + (size_t)bc * (N * 3);
    for (int j = tid; j < N; j += 512) {
        float x = posr[3 * j], y = posr[3 * j + 1], z = posr[3 * j + 2];
        sp[j] = make_float4(x, y, z, np_quad(x, y, z));
    }
    __syncthreads();

    const int rowA = rb + wave * 2, rowB = rowA + 1;
    const int nA = rowA & (N - 1), nB = nA + 1;
    const float4 meA = sp[nA];
    const float4 meB = sp[nB];

    // ---- pass 1: per-lane min of flipped dist-bits, both rows ----
    u32 mnA = 0xFFFFFFFFu, mnB = 0xFFFFFFFFu;
#pragma unroll
    for (int jj = 0; jj < 32; ++jj) {
        int j = jj * 64 + lane;
        float4 p = sp[j];
        mnA = umin_u32(mnA, flip_bits(np_dist(meA, p)));
        mnB = umin_u32(mnB, flip_bits(np_dist(meB, p)));
    }

    // ---- pivots: 33rd-smallest lane min (interleaved u32 bitonic) ----
    u32 vA = mnA, vB = mnB;
#pragma unroll
    for (int k = 2; k <= 64; k <<= 1) {
#pragma unroll
        for (int j = k >> 1; j > 0; j >>= 1) {
            u32 oA = (u32)__shfl_xor((int)vA, j);
            u32 oB = (u32)__shfl_xor((int)vB, j);
            bool keepmin = (((lane & k) == 0) == ((lane & j) == 0));
            vA = ((oA < vA) == keepmin) ? oA : vA;
            vB = ((oB < vB) == keepmin) ? oB : vB;
        }
    }
    u32 pdA = (u32)__builtin_amdgcn_readlane((int)vA, 32);
    u32 pdB = (u32)__builtin_amdgcn_readlane((int)vB, 32);

    // ---- pass 2: recompute + exec-masked ballot-prefix compact ----
    u64* slA = slots[wave * 2];
    u64* slB = slots[wave * 2 + 1];
    u32 baseA = 0, baseB = 0;
#pragma unroll 4
    for (int jj = 0; jj < 32; ++jj) {
        int j = jj * 64 + lane;
        float4 p = sp[j];
        u32 fA = flip_bits(np_dist(meA, p));
        u32 fB = flip_bits(np_dist(meB, p));
        bool sA = fA <= pdA;
        bool sB = fB <= pdB;
        u64 mA = __ballot(sA);
        u64 mB = __ballot(sB);
        if (sA) slA[baseA + mbcnt64(mA)] = ((u64)fA << 32) | (u32)j;
        if (sB) slB[baseB + mbcnt64(mB)] = ((u64)fB << 32) | (u32)j;
        baseA += (u32)__popcll(mA);
        baseB += (u32)__popcll(mB);
    }
    int cntA = (int)baseA, cntB = (int)baseB;

    if (cntA <= 128) emit_rank(slA, cntA, rowA, lane, edge_ws, dist_ws);
    else             slow_row(sp, meA, rowA, lane, edge_ws, dist_ws);
    if (cntB <= 128) emit_rank(slB, cntB, rowB, lane, edge_ws, dist_ws);
    else             slow_row(sp, meB, rowB, lane, edge_ws, dist_ws);
}

// ---------------------------------------------------------------------------
// Prep: transpose angle_weight [64][128] -> awT [128][64] in workspace.
// ---------------------------------------------------------------------------
__global__ void prep_kernel(const float* __restrict__ aw, float* __restrict__ awT) {
    int i = blockIdx.x * 256 + threadIdx.x;   // 8192
    awT[(i & 127) * 64 + (i >> 7)] = aw[i];
}

// ---------------------------------------------------------------------------
// Kernel 2: angle features + gate + gated aggregation + two 128->64 matvecs.
// One wave per (b,n); 8 consecutive n (same b) per 512-thread block.
// All intermediates wave-private in LDS -> only ONE barrier (outv transpose).
// Phase B: all-lane gather (lane -> cc=lane>>4, dd=lane&15) -- one 32-iter
// gather loop per row with all 64 lanes active.
// awT/sw read coalesced from global (L1/L2-resident, 32 KB each).
// ---------------------------------------------------------------------------
__global__ __launch_bounds__(512) void conv_kernel(
    const float* __restrict__ pos, const float* __restrict__ node_fea,
    const float* __restrict__ node_mask, const float* __restrict__ aw_t,
    const float* __restrict__ sw, const float* __restrict__ w1,
    const float* __restrict__ w2, const u16* __restrict__ edge_ws,
    const float* __restrict__ dist_ws, float* __restrict__ out) {
    __shared__ float theta_lds[8][128];    // [wave][kk*4+cc]
    __shared__ float gate_lds[8][128];     // [wave][cc*32+kk]
    __shared__ u16   edge_lds[8][128];     // [wave][cc*32+kk]
    __shared__ float h_lds[8][128];        // [wave][cc*32+dd]
    __shared__ float gsum_lds[8][4];       // [wave][cc]
    __shared__ float outv[8][65];          // [n-offset][m], padded

    const int tid  = threadIdx.x;
    const int lane = tid & 63;
    const int wave = tid >> 6;             // 0..7

    const int row0 = blockIdx.x * 8;   // (b,n) row base, same b across block
    const int b    = row0 >> 11;
    const int n0   = row0 & (N - 1);
    const int row  = row0 + wave;
    const int n    = row & (N - 1);
    const float mval = node_mask[b * N + n];

    // gate scalar S = sum_m relu(w1[m]) * w2[m]
    float S = wave_sum_dpp(fmaxf(w1[lane], 0.f) * w2[lane]);

    // ---- Phase A: per (cc,kk) pair: direction, theta, gate (wave-private) ----
#pragma unroll
    for (int it = 0; it < 2; ++it) {
        int p  = it * 64 + lane;
        int cc = p >> 5, kk = p & 31;
        int rowc = (b * C + cc) * N + n;
        int e      = edge_ws[(size_t)rowc * KNN + kk];
        float dist = dist_ws[(size_t)rowc * KNN + kk];
        const float* pp = pos + (size_t)rowc * 3;
        const float* qp = pos + ((size_t)(b * C + cc) * N + e) * 3;
        float dx = qp[0] - pp[0], dy = qp[1] - pp[1], dz = qp[2] - pp[2];
        float nrm = fmaxf(sqrtf(dx * dx + dy * dy + dz * dz), 1e-12f);
        float inv = 1.0f / nrm;
        dx *= inv; dy *= inv; dz *= inv;
        int src = lane & 32;   // lane holding kk==0 for this cc-group
        float n0x = __shfl(dx, src), n0y = __shfl(dy, src), n0z = __shfl(dz, src);
        float cosv = (kk == 0) ? 1.f : (dx * n0x + dy * n0y + dz * n0z);
        theta_lds[wave][kk * 4 + cc] = cosv * mval;

        float g = fmaxf(dist * S, 0.f) * mval;
        float gate = 1.f / (1.f + expf(-g));
        gate_lds[wave][cc * 32 + kk] = gate;
        edge_lds[wave][cc * 32 + kk] = (u16)e;
        float gs = gate;
#pragma unroll
        for (int off = 1; off < 32; off <<= 1) gs += __shfl_xor(gs, off);
        if (kk == 0) gsum_lds[wave][cc] = gs;
    }

    // ---- Phase B: h[f] = sum_k gate * fea_cat (all 64 lanes gather) ----
    {
        int cc = lane >> 4, dd = lane & 15;
        const float* nf = node_fea + (size_t)(b * C + cc) * N * D;
        float own = nf[(size_t)n * D + dd];
        h_lds[wave][cc * 32 + dd] = own * mval * gsum_lds[wave][cc];
        float acc = 0.f;
#pragma unroll
        for (int k = 0; k < 32; ++k) {
            int e = edge_lds[wave][cc * 32 + k];
            acc += gate_lds[wave][cc * 32 + k] * nf[(size_t)e * D + dd];
        }
        h_lds[wave][cc * 32 + 16 + dd] = acc * mval;
    }

    // ---- Phase C: m = lane; two 128->64 matvecs + epilogue ----
    float fs = 0.f, fe = 0.f;
#pragma unroll 8
    for (int f = 0; f < 128; ++f) {
        fs += aw_t[f * 64 + lane] * theta_lds[wave][f];
        fe += h_lds[wave][f] * sw[f * 64 + lane];
    }
    float v = fs + fe;
    v = (v > 0.f) ? v : 0.01f * v;
    outv[wave][lane] = v * mval;
    __syncthreads();   // the only cross-wave handoff (outv transpose)

    // store: thread t -> m = t>>3, n-offset j = t&7
    {
        int m = tid >> 3, j = tid & 7;
        out[((size_t)(b * 64 + m)) * N + n0 + j] = outv[j][m];
    }
}

// ---------------------------------------------------------------------------
extern "C" void kernel_launch(void* const* d_in, const int* in_sizes, int n_in,
                              void* d_out, int out_size, void* d_ws, size_t ws_size,
                              hipStream_t stream) {
    const float* pos       = (const float*)d_in[0];
    const float* node_fea  = (const float*)d_in[1];
    const float* node_mask = (const float*)d_in[2];
    const float* aw        = (const float*)d_in[3];
    const float* sw        = (const float*)d_in[4];
    const float* w1        = (const float*)d_in[5];
    const float* w2        = (const float*)d_in[6];
    float* out = (float*)d_out;

    // ws layout: dist f32 4 MB | edge u16 2 MB | awT 32 KB   (total ~6.03 MB)
    float* dist_ws = (float*)d_ws;
    u16*   edge_ws = (u16*)((char*)d_ws + 4u * 1024 * 1024);
    float* awT     = (float*)((char*)d_ws + 6u * 1024 * 1024);

    prep_kernel<<<32, 256, 0, stream>>>(aw, awT);
    knn_kernel<<<BS * C * N / 16, 512, 0, stream>>>(pos, edge_ws, dist_ws);
    conv_kernel<<<BS * N / 8, 512, 0, stream>>>(pos, node_fea, node_mask, awT, sw,
                                                w1, w2, edge_ws, dist_ws, out);
}

// Round 12
// 176.943 us; speedup vs baseline: 1.2595x; 1.0099x over previous
//
#include <hip/hip_runtime.h>
#include <math.h>

#define BS 4
#define C 4
#define N 2048
#define D 16
#define KNN 32
#define M 64

typedef unsigned long long u64;
typedef unsigned int u32;
typedef unsigned short u16;

// ---------------------------------------------------------------------------
// Kernel 1: exact 32-NN (sorted ascending, ties -> lower index) per (b,c,n).
// TWO rows per wave; 16 rows (same b,c) per 512-thread block.
// Pass 1 (interleaved): per-lane min of flipped dist-bits, both rows.
// Pivot pd = 33rd-smallest of the 64 lane minima (interleaved u32 bitonic).
// Guarantee: >=33 keys have distbits<=pd, so the top-33 always survive.
// Pass 2 (sequential per row, SHARED 128-slot buffer -> 40 KB LDS total ->
// 4 blocks/CU): recompute dists (bit-identical), exec-masked ballot-prefix
// compact of survivors (typ. ~46) into LDS; rank-sort via broadcast ds_read
// + u64 compares; ranks 1..32 store (rank 0 dropped = reference top-(k+1)).
// Register-light exact rescan fallback when cnt>124 (~never).
// Distance arithmetic replicates numpy f32 semantics bit-exactly:
//   inner = (x*x' + y*y') + z*z'   (sequential, no fma)
//   quad  = (x*x + y*y) + z*z
//   dist  = ((-2*inner) + quad_j) + quad_n
// ---------------------------------------------------------------------------

__device__ __forceinline__ u32 umin_u32(u32 a, u32 b) { return a < b ? a : b; }

#define DPP_MIN_STAGE(v, ctrl)                                                  \
    v = umin_u32(v, (u32)__builtin_amdgcn_update_dpp(                           \
                        (int)0xFFFFFFFF, (int)(v), (ctrl), 0xF, 0xF, false))

__device__ __forceinline__ u32 wave_min_dpp(u32 v) {
    DPP_MIN_STAGE(v, 0x111);
    DPP_MIN_STAGE(v, 0x112);
    DPP_MIN_STAGE(v, 0x114);
    DPP_MIN_STAGE(v, 0x118);
    DPP_MIN_STAGE(v, 0x142);
    DPP_MIN_STAGE(v, 0x143);
    return (u32)__builtin_amdgcn_readlane((int)v, 63);
}

#define DPP_ADD_STAGE(v, ctrl)                                                  \
    v += __int_as_float(__builtin_amdgcn_update_dpp(                            \
        0, __float_as_int(v), (ctrl), 0xF, 0xF, false))

__device__ __forceinline__ float wave_sum_dpp(float v) {
    DPP_ADD_STAGE(v, 0x111);
    DPP_ADD_STAGE(v, 0x112);
    DPP_ADD_STAGE(v, 0x114);
    DPP_ADD_STAGE(v, 0x118);
    DPP_ADD_STAGE(v, 0x142);
    DPP_ADD_STAGE(v, 0x143);
    return __int_as_float(__builtin_amdgcn_readlane(__float_as_int(v), 63));
}

__device__ __forceinline__ u32 mbcnt64(u64 m) {
    return __builtin_amdgcn_mbcnt_hi((u32)(m >> 32),
                                     __builtin_amdgcn_mbcnt_lo((u32)m, 0));
}

__device__ __forceinline__ float np_quad(float x, float y, float z) {
#pragma clang fp contract(off)
    float q = (x * x + y * y) + z * z;
    return q;
}

__device__ __forceinline__ float np_dist(const float4& me, const float4& p) {
#pragma clang fp contract(off)
    float inner = (me.x * p.x + me.y * p.y) + me.z * p.z;
    float dist  = ((-2.0f * inner) + p.w) + me.w;
    return dist;
}

__device__ __forceinline__ u32 flip_bits(float dist) {
    u32 b = __float_as_uint(dist);
    return b ^ (0x80000000u | (u32)((int)b >> 31));
}

__device__ __forceinline__ u64 dist_key(float dist, int j) {
    return ((u64)flip_bits(dist) << 32) | (u32)j;
}

// rank-sort survivors in sl[0..cnt) (cnt<=124) and emit ranks 1..32
__device__ __forceinline__ void emit_rank(u64* sl, int cnt, int row, int lane,
                                          u16* __restrict__ edge_ws,
                                          float* __restrict__ dist_ws) {
    if (lane < 4) sl[cnt + lane] = ~0ull;   // pads for the unroll-4 overshoot
    u64 own1 = sl[lane];
    if (lane >= cnt) own1 = ~0ull;
    int r1 = 0;
    for (int i = 0; i < cnt; i += 4) {
        u64 s0 = sl[i], s1 = sl[i + 1], s2 = sl[i + 2], s3 = sl[i + 3];
        r1 += (s0 < own1) + (s1 < own1) + (s2 < own1) + (s3 < own1);
    }
    if (r1 >= 1 && r1 <= KNN) {
        u32 fk = (u32)(own1 >> 32);
        u32 bb = (fk & 0x80000000u) ? (fk ^ 0x80000000u) : ~fk;
        edge_ws[(size_t)row * KNN + r1 - 1] = (u16)(u32)own1;
        dist_ws[(size_t)row * KNN + r1 - 1] = __uint_as_float(bb);
    }
    if (cnt > 64) {   // uncommon (~1%), wave-uniform
        u64 own2 = (64 + lane < cnt) ? sl[64 + lane] : ~0ull;
        int r2 = 0;
        for (int i = 0; i < cnt; i += 4) {
            u64 s0 = sl[i], s1 = sl[i + 1], s2 = sl[i + 2], s3 = sl[i + 3];
            r2 += (s0 < own2) + (s1 < own2) + (s2 < own2) + (s3 < own2);
        }
        if (r2 >= 1 && r2 <= KNN) {
            u32 fk = (u32)(own2 >> 32);
            u32 bb = (fk & 0x80000000u) ? (fk ^ 0x80000000u) : ~fk;
            edge_ws[(size_t)row * KNN + r2 - 1] = (u16)(u32)own2;
            dist_ws[(size_t)row * KNN + r2 - 1] = __uint_as_float(bb);
        }
    }
}

// register-light exact fallback (cnt>124, ~never): 33 rescan-extract rounds
__device__ __attribute__((noinline)) void slow_row(const float4* sp, float4 me,
                                                   int row, int lane,
                                                   u16* __restrict__ edge_ws,
                                                   float* __restrict__ dist_ws) {
    u64 thr = 0ull;   // all real keys are > 0 (flip==0 would require NaN dist)
    for (int s = 0; s <= KNN; ++s) {
        u64 best = ~0ull;
        for (int jj = 0; jj < 32; ++jj) {
            int j = jj * 64 + lane;
            u64 x = dist_key(np_dist(me, sp[j]), j);
            if (x > thr && x < best) best = x;
        }
        u32 bh = (u32)(best >> 32);
        u32 rh = wave_min_dpp(bh);
        u32 bl = (bh == rh) ? (u32)best : 0xFFFFFFFFu;
        u32 rl = wave_min_dpp(bl);
        thr = ((u64)rh << 32) | rl;
        if (s >= 1 && lane == s - 1) {
            u32 bb = (rh & 0x80000000u) ? (rh ^ 0x80000000u) : ~rh;
            edge_ws[(size_t)row * KNN + s - 1] = (u16)rl;
            dist_ws[(size_t)row * KNN + s - 1] = __uint_as_float(bb);
        }
    }
}

// one row's pass-2: compact survivors (distbits<=pd) into sl, then emit
__device__ __forceinline__ void compact_emit(const float4* sp, float4 me, u32 pd,
                                             u64* sl, int row, int lane,
                                             u16* __restrict__ edge_ws,
                                             float* __restrict__ dist_ws) {
    u32 base = 0;
#pragma unroll 2
    for (int jj = 0; jj < 32; ++jj) {
        int j = jj * 64 + lane;
        u32 f = flip_bits(np_dist(me, sp[j]));
        bool s = f <= pd;
        u64 m = __ballot(s);
        u32 pos = base + mbcnt64(m);
        if (s && pos < 128) sl[pos] = ((u64)f << 32) | (u32)j;
        base += (u32)__popcll(m);
    }
    if ((int)base <= 124) emit_rank(sl, (int)base, row, lane, edge_ws, dist_ws);
    else                  slow_row(sp, me, row, lane, edge_ws, dist_ws);
}

__global__ __launch_bounds__(512, 8) void knn_kernel(const float* __restrict__ pos,
                                                     u16* __restrict__ edge_ws,
                                                     float* __restrict__ dist_ws) {
    __shared__ float4 sp[N];          // 32 KB
    __shared__ u64 slots[8][128];     // 8 KB (shared by a wave's two rows)
    const int tid  = threadIdx.x;
    const int lane = tid & 63;
    const int wave = tid >> 6;          // 0..7
    const int rb   = blockIdx.x * 16;   // 16 rows per block, same (b,c)
    const int bc   = rb >> 11;

    const float* posr = pos + (size_t)bc * (N * 3);
    for (int j = tid; j < N; j += 512) {
        float x = posr[3 * j], y = posr[3 * j + 1], z = posr[3 * j + 2];
        sp[j] = make_float4(x, y, z, np_quad(x, y, z));
    }
    __syncthreads();

    const int rowA = rb + wave * 2, rowB = rowA + 1;
    const int nA = rowA & (N - 1), nB = nA + 1;
    const float4 meA = sp[nA];
    const float4 meB = sp[nB];

    // ---- pass 1: per-lane min of flipped dist-bits, both rows ----
    u32 mnA = 0xFFFFFFFFu, mnB = 0xFFFFFFFFu;
#pragma unroll
    for (int jj = 0; jj < 32; ++jj) {
        int j = jj * 64 + lane;
        float4 p = sp[j];
        mnA = umin_u32(mnA, flip_bits(np_dist(meA, p)));
        mnB = umin_u32(mnB, flip_bits(np_dist(meB, p)));
    }

    // ---- pivots: 33rd-smallest lane min (interleaved u32 bitonic) ----
    u32 vA = mnA, vB = mnB;
#pragma unroll
    for (int k = 2; k <= 64; k <<= 1) {
#pragma unroll
        for (int j = k >> 1; j > 0; j >>= 1) {
            u32 oA = (u32)__shfl_xor((int)vA, j);
            u32 oB = (u32)__shfl_xor((int)vB, j);
            bool keepmin = (((lane & k) == 0) == ((lane & j) == 0));
            vA = ((oA < vA) == keepmin) ? oA : vA;
            vB = ((oB < vB) == keepmin) ? oB : vB;
        }
    }
    u32 pdA = (u32)__builtin_amdgcn_readlane((int)vA, 32);
    u32 pdB = (u32)__builtin_amdgcn_readlane((int)vB, 32);

    // ---- pass 2: sequential per row, shared slot buffer ----
    compact_emit(sp, meA, pdA, slots[wave], rowA, lane, edge_ws, dist_ws);
    compact_emit(sp, meB, pdB, slots[wave], rowB, lane, edge_ws, dist_ws);
}

// ---------------------------------------------------------------------------
// Prep: repack angle_weight^T and scalar_weight into [f/4][m][f%4] f32 layout
// so conv Phase C reads one dwordx4 per weight per 4 f-values.
// ---------------------------------------------------------------------------
__global__ void prep_kernel(const float* __restrict__ aw, const float* __restrict__ sw,
                            float* __restrict__ aw4, float* __restrict__ sw4) {
    int i = blockIdx.x * 256 + threadIdx.x;   // 0..8191, i = f*64 + m
    int f = i >> 6, m = i & 63;
    int idx = (f >> 2) * 256 + m * 4 + (f & 3);
    aw4[idx] = aw[m * 128 + f];
    sw4[idx] = sw[i];
}

// ---------------------------------------------------------------------------
// Kernel 2: angle features + gate + gated aggregation + two 128->64 matvecs.
// One wave per (b,n); 8 consecutive n (same b) per 512-thread block.
// All intermediates wave-private in LDS -> only ONE barrier (outv transpose).
// Phase C: float4 weights from global (VMEM pipe) x float4 theta/h broadcast
// from LDS -> 4x fewer ops on both pipes, pipes overlap.
// ---------------------------------------------------------------------------
__global__ __launch_bounds__(512) void conv_kernel(
    const float* __restrict__ pos, const float* __restrict__ node_fea,
    const float* __restrict__ node_mask, const float* __restrict__ aw4,
    const float* __restrict__ sw4, const float* __restrict__ w1,
    const float* __restrict__ w2, const u16* __restrict__ edge_ws,
    const float* __restrict__ dist_ws, float* __restrict__ out) {
    __shared__ __align__(16) float theta_lds[8][128];  // [wave][f], f=kk*4+cc
    __shared__ float gate_lds[8][128];                 // [wave][cc*32+kk]
    __shared__ u16   edge_lds[8][128];                 // [wave][cc*32+kk]
    __shared__ __align__(16) float h_lds[8][128];      // [wave][f], f=cc*32+..
    __shared__ float gsum_lds[8][4];                   // [wave][cc]
    __shared__ float outv[8][65];                      // [n-offset][m], padded

    const int tid  = threadIdx.x;
    const int lane = tid & 63;
    const int wave = tid >> 6;             // 0..7

    const int row0 = blockIdx.x * 8;   // (b,n) row base, same b across block
    const int b    = row0 >> 11;
    const int n0   = row0 & (N - 1);
    const int row  = row0 + wave;
    const int n    = row & (N - 1);
    const float mval = node_mask[b * N + n];

    // gate scalar S = sum_m relu(w1[m]) * w2[m]
    float S = wave_sum_dpp(fmaxf(w1[lane], 0.f) * w2[lane]);

    // ---- Phase A: per (cc,kk) pair: direction, theta, gate (wave-private) ----
#pragma unroll
    for (int it = 0; it < 2; ++it) {
        int p  = it * 64 + lane;
        int cc = p >> 5, kk = p & 31;
        int rowc = (b * C + cc) * N + n;
        int e      = edge_ws[(size_t)rowc * KNN + kk];
        float dist = dist_ws[(size_t)rowc * KNN + kk];
        const float* pp = pos + (size_t)rowc * 3;
        const float* qp = pos + ((size_t)(b * C + cc) * N + e) * 3;
        float dx = qp[0] - pp[0], dy = qp[1] - pp[1], dz = qp[2] - pp[2];
        float nrm = fmaxf(sqrtf(dx * dx + dy * dy + dz * dz), 1e-12f);
        float inv = 1.0f / nrm;
        dx *= inv; dy *= inv; dz *= inv;
        int src = lane & 32;   // lane holding kk==0 for this cc-group
        float n0x = __shfl(dx, src), n0y = __shfl(dy, src), n0z = __shfl(dz, src);
        float cosv = (kk == 0) ? 1.f : (dx * n0x + dy * n0y + dz * n0z);
        theta_lds[wave][kk * 4 + cc] = cosv * mval;

        float g = fmaxf(dist * S, 0.f) * mval;
        float gate = 1.f / (1.f + expf(-g));
        gate_lds[wave][cc * 32 + kk] = gate;
        edge_lds[wave][cc * 32 + kk] = (u16)e;
        float gs = gate;
#pragma unroll
        for (int off = 1; off < 32; off <<= 1) gs += __shfl_xor(gs, off);
        if (kk == 0) gsum_lds[wave][cc] = gs;
    }

    // ---- Phase B: h[f] = sum_k gate * fea_cat (all 64 lanes gather) ----
    {
        int cc = lane >> 4, dd = lane & 15;
        const float* nf = node_fea + (size_t)(b * C + cc) * N * D;
        float own = nf[(size_t)n * D + dd];
        h_lds[wave][cc * 32 + dd] = own * mval * gsum_lds[wave][cc];
        float acc = 0.f;
#pragma unroll
        for (int k = 0; k < 32; ++k) {
            int e = edge_lds[wave][cc * 32 + k];
            acc += gate_lds[wave][cc * 32 + k] * nf[(size_t)e * D + dd];
        }
        h_lds[wave][cc * 32 + 16 + dd] = acc * mval;
    }

    // ---- Phase C: m = lane; two 128->64 matvecs (float4) + epilogue ----
    {
        const float4* wa4 = (const float4*)aw4;
        const float4* wv4 = (const float4*)sw4;
        const float4* th4 = (const float4*)(&theta_lds[wave][0]);
        const float4* hh4 = (const float4*)(&h_lds[wave][0]);
        float fs = 0.f, fe = 0.f;
#pragma unroll 8
        for (int f4 = 0; f4 < 32; ++f4) {
            float4 wa = wa4[f4 * 64 + lane];
            float4 wv = wv4[f4 * 64 + lane];
            float4 tv = th4[f4];
            float4 hv = hh4[f4];
            fs += wa.x * tv.x + wa.y * tv.y + wa.z * tv.z + wa.w * tv.w;
            fe += wv.x * hv.x + wv.y * hv.y + wv.z * hv.z + wv.w * hv.w;
        }
        float v = fs + fe;
        v = (v > 0.f) ? v : 0.01f * v;
        outv[wave][lane] = v * mval;
    }
    __syncthreads();   // the only cross-wave handoff (outv transpose)

    // store: thread t -> m = t>>3, n-offset j = t&7
    {
        int m = tid >> 3, j = tid & 7;
        out[((size_t)(b * 64 + m)) * N + n0 + j] = outv[j][m];
    }
}

// ---------------------------------------------------------------------------
extern "C" void kernel_launch(void* const* d_in, const int* in_sizes, int n_in,
                              void* d_out, int out_size, void* d_ws, size_t ws_size,
                              hipStream_t stream) {
    const float* pos       = (const float*)d_in[0];
    const float* node_fea  = (const float*)d_in[1];
    const float* node_mask = (const float*)d_in[2];
    const float* aw        = (const float*)d_in[3];
    const float* sw        = (const float*)d_in[4];
    const float* w1        = (const float*)d_in[5];
    const float* w2        = (const float*)d_in[6];
    float* out = (float*)d_out;

    // ws: dist f32 4 MB | edge u16 2 MB | aw4 32 KB | sw4 32 KB  (~6.1 MB)
    float* dist_ws = (float*)d_ws;
    u16*   edge_ws = (u16*)((char*)d_ws + 4u * 1024 * 1024);
    float* aw4     = (float*)((char*)d_ws + 6u * 1024 * 1024);
    float* sw4     = (float*)((char*)d_ws + 6u * 1024 * 1024 + 32u * 1024);

    prep_kernel<<<32, 256, 0, stream>>>(aw, sw, aw4, sw4);
    knn_kernel<<<BS * C * N / 16, 512, 0, stream>>>(pos, edge_ws, dist_ws);
    conv_kernel<<<BS * N / 8, 512, 0, stream>>>(pos, node_fea, node_mask, aw4, sw4,
                                                w1, w2, edge_ws, dist_ws, out);
}

// Round 13
// 153.816 us; speedup vs baseline: 1.4489x; 1.1504x over previous
//
#include <hip/hip_runtime.h>
#include <math.h>

#define BS 4
#define C 4
#define N 2048
#define D 16
#define KNN 32
#define M 64

typedef unsigned long long u64;
typedef unsigned int u32;
typedef unsigned short u16;

// ---------------------------------------------------------------------------
// Kernel 1: exact 32-NN (sorted ascending, ties -> lower index) per (b,c,n).
// TWO rows per wave; 16 rows (same b,c) per 512-thread block.
// Pass 1 (interleaved, unroll 8 to bound VGPR pipelining): per-lane min of
// flipped dist-bits, both rows. Pivot pd = 33rd-smallest of the 64 lane
// minima (interleaved u32 bitonic). Guarantee: >=33 keys have distbits<=pd.
// Pass 2 (sequential per row, shared 128-slot buffer, 40 KB LDS total):
// recompute dists (bit-identical), exec-masked ballot-prefix compact of
// survivors (typ. ~46) into LDS; rank-sort via broadcast ds_read + u64
// compares; ranks 1..32 store (rank 0 dropped = reference top-(k+1)).
// Register-light exact rescan fallback when cnt>124 (~never).
// launch_bounds(512,6): VGPR cap ~85 -- R12's (512,8) forced VGPR=32 and
// spilled 200 MB/launch to scratch (FETCH 67 MB, WRITE 137 MB, 2.4 TB/s).
// Distance arithmetic replicates numpy f32 semantics bit-exactly:
//   inner = (x*x' + y*y') + z*z'   (sequential, no fma)
//   quad  = (x*x + y*y) + z*z
//   dist  = ((-2*inner) + quad_j) + quad_n
// ---------------------------------------------------------------------------

__device__ __forceinline__ u32 umin_u32(u32 a, u32 b) { return a < b ? a : b; }

#define DPP_MIN_STAGE(v, ctrl)                                                  \
    v = umin_u32(v, (u32)__builtin_amdgcn_update_dpp(                           \
                        (int)0xFFFFFFFF, (int)(v), (ctrl), 0xF, 0xF, false))

__device__ __forceinline__ u32 wave_min_dpp(u32 v) {
    DPP_MIN_STAGE(v, 0x111);
    DPP_MIN_STAGE(v, 0x112);
    DPP_MIN_STAGE(v, 0x114);
    DPP_MIN_STAGE(v, 0x118);
    DPP_MIN_STAGE(v, 0x142);
    DPP_MIN_STAGE(v, 0x143);
    return (u32)__builtin_amdgcn_readlane((int)v, 63);
}

#define DPP_ADD_STAGE(v, ctrl)                                                  \
    v += __int_as_float(__builtin_amdgcn_update_dpp(                            \
        0, __float_as_int(v), (ctrl), 0xF, 0xF, false))

__device__ __forceinline__ float wave_sum_dpp(float v) {
    DPP_ADD_STAGE(v, 0x111);
    DPP_ADD_STAGE(v, 0x112);
    DPP_ADD_STAGE(v, 0x114);
    DPP_ADD_STAGE(v, 0x118);
    DPP_ADD_STAGE(v, 0x142);
    DPP_ADD_STAGE(v, 0x143);
    return __int_as_float(__builtin_amdgcn_readlane(__float_as_int(v), 63));
}

__device__ __forceinline__ u32 mbcnt64(u64 m) {
    return __builtin_amdgcn_mbcnt_hi((u32)(m >> 32),
                                     __builtin_amdgcn_mbcnt_lo((u32)m, 0));
}

__device__ __forceinline__ float np_quad(float x, float y, float z) {
#pragma clang fp contract(off)
    float q = (x * x + y * y) + z * z;
    return q;
}

__device__ __forceinline__ float np_dist(const float4& me, const float4& p) {
#pragma clang fp contract(off)
    float inner = (me.x * p.x + me.y * p.y) + me.z * p.z;
    float dist  = ((-2.0f * inner) + p.w) + me.w;
    return dist;
}

__device__ __forceinline__ u32 flip_bits(float dist) {
    u32 b = __float_as_uint(dist);
    return b ^ (0x80000000u | (u32)((int)b >> 31));
}

__device__ __forceinline__ u64 dist_key(float dist, int j) {
    return ((u64)flip_bits(dist) << 32) | (u32)j;
}

// rank-sort survivors in sl[0..cnt) (cnt<=124) and emit ranks 1..32
__device__ __forceinline__ void emit_rank(u64* sl, int cnt, int row, int lane,
                                          u16* __restrict__ edge_ws,
                                          float* __restrict__ dist_ws) {
    if (lane < 4) sl[cnt + lane] = ~0ull;   // pads for the unroll-4 overshoot
    u64 own1 = sl[lane];
    if (lane >= cnt) own1 = ~0ull;
    int r1 = 0;
    for (int i = 0; i < cnt; i += 4) {
        u64 s0 = sl[i], s1 = sl[i + 1], s2 = sl[i + 2], s3 = sl[i + 3];
        r1 += (s0 < own1) + (s1 < own1) + (s2 < own1) + (s3 < own1);
    }
    if (r1 >= 1 && r1 <= KNN) {
        u32 fk = (u32)(own1 >> 32);
        u32 bb = (fk & 0x80000000u) ? (fk ^ 0x80000000u) : ~fk;
        edge_ws[(size_t)row * KNN + r1 - 1] = (u16)(u32)own1;
        dist_ws[(size_t)row * KNN + r1 - 1] = __uint_as_float(bb);
    }
    if (cnt > 64) {   // uncommon (~1%), wave-uniform
        u64 own2 = (64 + lane < cnt) ? sl[64 + lane] : ~0ull;
        int r2 = 0;
        for (int i = 0; i < cnt; i += 4) {
            u64 s0 = sl[i], s1 = sl[i + 1], s2 = sl[i + 2], s3 = sl[i + 3];
            r2 += (s0 < own2) + (s1 < own2) + (s2 < own2) + (s3 < own2);
        }
        if (r2 >= 1 && r2 <= KNN) {
            u32 fk = (u32)(own2 >> 32);
            u32 bb = (fk & 0x80000000u) ? (fk ^ 0x80000000u) : ~fk;
            edge_ws[(size_t)row * KNN + r2 - 1] = (u16)(u32)own2;
            dist_ws[(size_t)row * KNN + r2 - 1] = __uint_as_float(bb);
        }
    }
}

// register-light exact fallback (cnt>124, ~never): 33 rescan-extract rounds
__device__ __attribute__((noinline)) void slow_row(const float4* sp, float4 me,
                                                   int row, int lane,
                                                   u16* __restrict__ edge_ws,
                                                   float* __restrict__ dist_ws) {
    u64 thr = 0ull;   // all real keys are > 0 (flip==0 would require NaN dist)
    for (int s = 0; s <= KNN; ++s) {
        u64 best = ~0ull;
        for (int jj = 0; jj < 32; ++jj) {
            int j = jj * 64 + lane;
            u64 x = dist_key(np_dist(me, sp[j]), j);
            if (x > thr && x < best) best = x;
        }
        u32 bh = (u32)(best >> 32);
        u32 rh = wave_min_dpp(bh);
        u32 bl = (bh == rh) ? (u32)best : 0xFFFFFFFFu;
        u32 rl = wave_min_dpp(bl);
        thr = ((u64)rh << 32) | rl;
        if (s >= 1 && lane == s - 1) {
            u32 bb = (rh & 0x80000000u) ? (rh ^ 0x80000000u) : ~rh;
            edge_ws[(size_t)row * KNN + s - 1] = (u16)rl;
            dist_ws[(size_t)row * KNN + s - 1] = __uint_as_float(bb);
        }
    }
}

// one row's pass-2: compact survivors (distbits<=pd) into sl, then emit
__device__ __forceinline__ void compact_emit(const float4* sp, float4 me, u32 pd,
                                             u64* sl, int row, int lane,
                                             u16* __restrict__ edge_ws,
                                             float* __restrict__ dist_ws) {
    u32 base = 0;
#pragma unroll 2
    for (int jj = 0; jj < 32; ++jj) {
        int j = jj * 64 + lane;
        u32 f = flip_bits(np_dist(me, sp[j]));
        bool s = f <= pd;
        u64 m = __ballot(s);
        u32 pos = base + mbcnt64(m);
        if (s && pos < 128) sl[pos] = ((u64)f << 32) | (u32)j;
        base += (u32)__popcll(m);
    }
    if ((int)base <= 124) emit_rank(sl, (int)base, row, lane, edge_ws, dist_ws);
    else                  slow_row(sp, me, row, lane, edge_ws, dist_ws);
}

__global__ __launch_bounds__(512, 6) void knn_kernel(const float* __restrict__ pos,
                                                     u16* __restrict__ edge_ws,
                                                     float* __restrict__ dist_ws) {
    __shared__ float4 sp[N];          // 32 KB
    __shared__ u64 slots[8][128];     // 8 KB (shared by a wave's two rows)
    const int tid  = threadIdx.x;
    const int lane = tid & 63;
    const int wave = tid >> 6;          // 0..7
    const int rb   = blockIdx.x * 16;   // 16 rows per block, same (b,c)
    const int bc   = rb >> 11;

    const float* posr = pos + (size_t)bc * (N * 3);
    for (int j = tid; j < N; j += 512) {
        float x = posr[3 * j], y = posr[3 * j + 1], z = posr[3 * j + 2];
        sp[j] = make_float4(x, y, z, np_quad(x, y, z));
    }
    __syncthreads();

    const int rowA = rb + wave * 2, rowB = rowA + 1;
    const int nA = rowA & (N - 1), nB = nA + 1;
    const float4 meA = sp[nA];
    const float4 meB = sp[nB];

    // ---- pass 1: per-lane min of flipped dist-bits, both rows ----
    u32 mnA = 0xFFFFFFFFu, mnB = 0xFFFFFFFFu;
#pragma unroll 8
    for (int jj = 0; jj < 32; ++jj) {
        int j = jj * 64 + lane;
        float4 p = sp[j];
        mnA = umin_u32(mnA, flip_bits(np_dist(meA, p)));
        mnB = umin_u32(mnB, flip_bits(np_dist(meB, p)));
    }

    // ---- pivots: 33rd-smallest lane min (interleaved u32 bitonic) ----
    u32 vA = mnA, vB = mnB;
#pragma unroll
    for (int k = 2; k <= 64; k <<= 1) {
#pragma unroll
        for (int j = k >> 1; j > 0; j >>= 1) {
            u32 oA = (u32)__shfl_xor((int)vA, j);
            u32 oB = (u32)__shfl_xor((int)vB, j);
            bool keepmin = (((lane & k) == 0) == ((lane & j) == 0));
            vA = ((oA < vA) == keepmin) ? oA : vA;
            vB = ((oB < vB) == keepmin) ? oB : vB;
        }
    }
    u32 pdA = (u32)__builtin_amdgcn_readlane((int)vA, 32);
    u32 pdB = (u32)__builtin_amdgcn_readlane((int)vB, 32);

    // ---- pass 2: sequential per row, shared slot buffer ----
    compact_emit(sp, meA, pdA, slots[wave], rowA, lane, edge_ws, dist_ws);
    compact_emit(sp, meB, pdB, slots[wave], rowB, lane, edge_ws, dist_ws);
}

// ---------------------------------------------------------------------------
// Prep: repack angle_weight^T and scalar_weight into [f/4][m][f%4] f32 layout
// so conv Phase C reads one dwordx4 per weight per 4 f-values.
// ---------------------------------------------------------------------------
__global__ void prep_kernel(const float* __restrict__ aw, const float* __restrict__ sw,
                            float* __restrict__ aw4, float* __restrict__ sw4) {
    int i = blockIdx.x * 256 + threadIdx.x;   // 0..8191, i = f*64 + m
    int f = i >> 6, m = i & 63;
    int idx = (f >> 2) * 256 + m * 4 + (f & 3);
    aw4[idx] = aw[m * 128 + f];
    sw4[idx] = sw[i];
}

// ---------------------------------------------------------------------------
// Kernel 2: angle features + gate + gated aggregation + two 128->64 matvecs.
// One wave per (b,n); 8 consecutive n (same b) per 512-thread block.
// All intermediates wave-private in LDS -> only ONE barrier (outv transpose).
// Phase C: float4 weights from global (VMEM pipe) x float4 theta/h broadcast
// from LDS; unroll 4 to bound in-flight float4 register pressure.
// ---------------------------------------------------------------------------
__global__ __launch_bounds__(512) void conv_kernel(
    const float* __restrict__ pos, const float* __restrict__ node_fea,
    const float* __restrict__ node_mask, const float* __restrict__ aw4,
    const float* __restrict__ sw4, const float* __restrict__ w1,
    const float* __restrict__ w2, const u16* __restrict__ edge_ws,
    const float* __restrict__ dist_ws, float* __restrict__ out) {
    __shared__ __align__(16) float theta_lds[8][128];  // [wave][f], f=kk*4+cc
    __shared__ float gate_lds[8][128];                 // [wave][cc*32+kk]
    __shared__ u16   edge_lds[8][128];                 // [wave][cc*32+kk]
    __shared__ __align__(16) float h_lds[8][128];      // [wave][f], f=cc*32+..
    __shared__ float gsum_lds[8][4];                   // [wave][cc]
    __shared__ float outv[8][65];                      // [n-offset][m], padded

    const int tid  = threadIdx.x;
    const int lane = tid & 63;
    const int wave = tid >> 6;             // 0..7

    const int row0 = blockIdx.x * 8;   // (b,n) row base, same b across block
    const int b    = row0 >> 11;
    const int n0   = row0 & (N - 1);
    const int row  = row0 + wave;
    const int n    = row & (N - 1);
    const float mval = node_mask[b * N + n];

    // gate scalar S = sum_m relu(w1[m]) * w2[m]
    float S = wave_sum_dpp(fmaxf(w1[lane], 0.f) * w2[lane]);

    // ---- Phase A: per (cc,kk) pair: direction, theta, gate (wave-private) ----
#pragma unroll
    for (int it = 0; it < 2; ++it) {
        int p  = it * 64 + lane;
        int cc = p >> 5, kk = p & 31;
        int rowc = (b * C + cc) * N + n;
        int e      = edge_ws[(size_t)rowc * KNN + kk];
        float dist = dist_ws[(size_t)rowc * KNN + kk];
        const float* pp = pos + (size_t)rowc * 3;
        const float* qp = pos + ((size_t)(b * C + cc) * N + e) * 3;
        float dx = qp[0] - pp[0], dy = qp[1] - pp[1], dz = qp[2] - pp[2];
        float nrm = fmaxf(sqrtf(dx * dx + dy * dy + dz * dz), 1e-12f);
        float inv = 1.0f / nrm;
        dx *= inv; dy *= inv; dz *= inv;
        int src = lane & 32;   // lane holding kk==0 for this cc-group
        float n0x = __shfl(dx, src), n0y = __shfl(dy, src), n0z = __shfl(dz, src);
        float cosv = (kk == 0) ? 1.f : (dx * n0x + dy * n0y + dz * n0z);
        theta_lds[wave][kk * 4 + cc] = cosv * mval;

        float g = fmaxf(dist * S, 0.f) * mval;
        float gate = 1.f / (1.f + expf(-g));
        gate_lds[wave][cc * 32 + kk] = gate;
        edge_lds[wave][cc * 32 + kk] = (u16)e;
        float gs = gate;
#pragma unroll
        for (int off = 1; off < 32; off <<= 1) gs += __shfl_xor(gs, off);
        if (kk == 0) gsum_lds[wave][cc] = gs;
    }

    // ---- Phase B: h[f] = sum_k gate * fea_cat (all 64 lanes gather) ----
    {
        int cc = lane >> 4, dd = lane & 15;
        const float* nf = node_fea + (size_t)(b * C + cc) * N * D;
        float own = nf[(size_t)n * D + dd];
        h_lds[wave][cc * 32 + dd] = own * mval * gsum_lds[wave][cc];
        float acc = 0.f;
#pragma unroll
        for (int k = 0; k < 32; ++k) {
            int e = edge_lds[wave][cc * 32 + k];
            acc += gate_lds[wave][cc * 32 + k] * nf[(size_t)e * D + dd];
        }
        h_lds[wave][cc * 32 + 16 + dd] = acc * mval;
    }

    // ---- Phase C: m = lane; two 128->64 matvecs (float4) + epilogue ----
    {
        const float4* wa4 = (const float4*)aw4;
        const float4* wv4 = (const float4*)sw4;
        const float4* th4 = (const float4*)(&theta_lds[wave][0]);
        const float4* hh4 = (const float4*)(&h_lds[wave][0]);
        float fs = 0.f, fe = 0.f;
#pragma unroll 4
        for (int f4 = 0; f4 < 32; ++f4) {
            float4 wa = wa4[f4 * 64 + lane];
            float4 wv = wv4[f4 * 64 + lane];
            float4 tv = th4[f4];
            float4 hv = hh4[f4];
            fs += wa.x * tv.x + wa.y * tv.y + wa.z * tv.z + wa.w * tv.w;
            fe += wv.x * hv.x + wv.y * hv.y + wv.z * hv.z + wv.w * hv.w;
        }
        float v = fs + fe;
        v = (v > 0.f) ? v : 0.01f * v;
        outv[wave][lane] = v * mval;
    }
    __syncthreads();   // the only cross-wave handoff (outv transpose)

    // store: thread t -> m = t>>3, n-offset j = t&7
    {
        int m = tid >> 3, j = tid & 7;
        out[((size_t)(b * 64 + m)) * N + n0 + j] = outv[j][m];
    }
}

// ---------------------------------------------------------------------------
extern "C" void kernel_launch(void* const* d_in, const int* in_sizes, int n_in,
                              void* d_out, int out_size, void* d_ws, size_t ws_size,
                              hipStream_t stream) {
    const float* pos       = (const float*)d_in[0];
    const float* node_fea  = (const float*)d_in[1];
    const float* node_mask = (const float*)d_in[2];
    const float* aw        = (const float*)d_in[3];
    const float* sw        = (const float*)d_in[4];
    const float* w1        = (const float*)d_in[5];
    const float* w2        = (const float*)d_in[6];
    float* out = (float*)d_out;

    // ws: dist f32 4 MB | edge u16 2 MB | aw4 32 KB | sw4 32 KB  (~6.1 MB)
    float* dist_ws = (float*)d_ws;
    u16*   edge_ws = (u16*)((char*)d_ws + 4u * 1024 * 1024);
    float* aw4     = (float*)((char*)d_ws + 6u * 1024 * 1024);
    float* sw4     = (float*)((char*)d_ws + 6u * 1024 * 1024 + 32u * 1024);

    prep_kernel<<<32, 256, 0, stream>>>(aw, sw, aw4, sw4);
    knn_kernel<<<BS * C * N / 16, 512, 0, stream>>>(pos, edge_ws, dist_ws);
    conv_kernel<<<BS * N / 8, 512, 0, stream>>>(pos, node_fea, node_mask, aw4, sw4,
                                                w1, w2, edge_ws, dist_ws, out);
}

// Round 14
// 144.596 us; speedup vs baseline: 1.5413x; 1.0638x over previous
//
#include <hip/hip_runtime.h>
#include <math.h>

#define BS 4
#define C 4
#define N 2048
#define D 16
#define KNN 32
#define M 64

typedef unsigned long long u64;
typedef unsigned int u32;
typedef unsigned short u16;

// ---------------------------------------------------------------------------
// Kernel 1: exact 32-NN (sorted ascending, ties -> lower index) per (b,c,n).
// TWO rows per wave; 16 rows (same b,c) per 512-thread block.
// Pass 1: per-lane v_min_f32 of raw dists (float order == flipped-bit order
// here: no NaNs, no -0.0 -- dist==0 always rounds to +0). Pivot pd =
// 33rd-smallest of the 64 lane minima (float bitonic). Guarantee: >=33 keys
// have dist<=pd, so the top-33 always survive.
// Pass 2: recompute dists (bit-identical), one v_cmp_le_f32 vs pd, exec-masked
// ballot-prefix compact of survivors (typ. ~46) into LDS as u64 (flip bits
// computed for survivors only); rank-sort via broadcast ds_read + u64
// compares; ranks 1..32 store (rank 0 dropped = reference top-(k+1)).
// Register-light exact rescan fallback when cnt>124 (~never).
// launch_bounds(512,6): VGPR cap ~85 (R12's (512,8) forced VGPR=32 -> 200 MB
// scratch spill). Block 0 additionally repacks aw4/sw4 (fused prep).
// Distance arithmetic replicates numpy f32 semantics bit-exactly:
//   inner = (x*x' + y*y') + z*z'   (sequential, no fma)
//   quad  = (x*x + y*y) + z*z
//   dist  = ((-2*inner) + quad_j) + quad_n   (-2*inner exact -> fma-safe)
// ---------------------------------------------------------------------------

__device__ __forceinline__ u32 umin_u32(u32 a, u32 b) { return a < b ? a : b; }

#define DPP_MIN_STAGE(v, ctrl)                                                  \
    v = umin_u32(v, (u32)__builtin_amdgcn_update_dpp(                           \
                        (int)0xFFFFFFFF, (int)(v), (ctrl), 0xF, 0xF, false))

__device__ __forceinline__ u32 wave_min_dpp(u32 v) {
    DPP_MIN_STAGE(v, 0x111);
    DPP_MIN_STAGE(v, 0x112);
    DPP_MIN_STAGE(v, 0x114);
    DPP_MIN_STAGE(v, 0x118);
    DPP_MIN_STAGE(v, 0x142);
    DPP_MIN_STAGE(v, 0x143);
    return (u32)__builtin_amdgcn_readlane((int)v, 63);
}

#define DPP_ADD_STAGE(v, ctrl)                                                  \
    v += __int_as_float(__builtin_amdgcn_update_dpp(                            \
        0, __float_as_int(v), (ctrl), 0xF, 0xF, false))

__device__ __forceinline__ float wave_sum_dpp(float v) {
    DPP_ADD_STAGE(v, 0x111);
    DPP_ADD_STAGE(v, 0x112);
    DPP_ADD_STAGE(v, 0x114);
    DPP_ADD_STAGE(v, 0x118);
    DPP_ADD_STAGE(v, 0x142);
    DPP_ADD_STAGE(v, 0x143);
    return __int_as_float(__builtin_amdgcn_readlane(__float_as_int(v), 63));
}

__device__ __forceinline__ u32 mbcnt64(u64 m) {
    return __builtin_amdgcn_mbcnt_hi((u32)(m >> 32),
                                     __builtin_amdgcn_mbcnt_lo((u32)m, 0));
}

__device__ __forceinline__ float np_quad(float x, float y, float z) {
#pragma clang fp contract(off)
    float q = (x * x + y * y) + z * z;
    return q;
}

__device__ __forceinline__ float np_dist(const float4& me, const float4& p) {
#pragma clang fp contract(off)
    float inner = (me.x * p.x + me.y * p.y) + me.z * p.z;
    float dist  = ((-2.0f * inner) + p.w) + me.w;
    return dist;
}

__device__ __forceinline__ u32 flip_bits(float dist) {
    u32 b = __float_as_uint(dist);
    return b ^ (0x80000000u | (u32)((int)b >> 31));
}

__device__ __forceinline__ u64 dist_key(float dist, int j) {
    return ((u64)flip_bits(dist) << 32) | (u32)j;
}

// rank-sort survivors in sl[0..cnt) (cnt<=124) and emit ranks 1..32
__device__ __forceinline__ void emit_rank(u64* sl, int cnt, int row, int lane,
                                          u16* __restrict__ edge_ws,
                                          float* __restrict__ dist_ws) {
    if (lane < 4) sl[cnt + lane] = ~0ull;   // pads for the unroll-4 overshoot
    u64 own1 = sl[lane];
    if (lane >= cnt) own1 = ~0ull;
    int r1 = 0;
    for (int i = 0; i < cnt; i += 4) {
        u64 s0 = sl[i], s1 = sl[i + 1], s2 = sl[i + 2], s3 = sl[i + 3];
        r1 += (s0 < own1) + (s1 < own1) + (s2 < own1) + (s3 < own1);
    }
    if (r1 >= 1 && r1 <= KNN) {
        u32 fk = (u32)(own1 >> 32);
        u32 bb = (fk & 0x80000000u) ? (fk ^ 0x80000000u) : ~fk;
        edge_ws[(size_t)row * KNN + r1 - 1] = (u16)(u32)own1;
        dist_ws[(size_t)row * KNN + r1 - 1] = __uint_as_float(bb);
    }
    if (cnt > 64) {   // uncommon (~1%), wave-uniform
        u64 own2 = (64 + lane < cnt) ? sl[64 + lane] : ~0ull;
        int r2 = 0;
        for (int i = 0; i < cnt; i += 4) {
            u64 s0 = sl[i], s1 = sl[i + 1], s2 = sl[i + 2], s3 = sl[i + 3];
            r2 += (s0 < own2) + (s1 < own2) + (s2 < own2) + (s3 < own2);
        }
        if (r2 >= 1 && r2 <= KNN) {
            u32 fk = (u32)(own2 >> 32);
            u32 bb = (fk & 0x80000000u) ? (fk ^ 0x80000000u) : ~fk;
            edge_ws[(size_t)row * KNN + r2 - 1] = (u16)(u32)own2;
            dist_ws[(size_t)row * KNN + r2 - 1] = __uint_as_float(bb);
        }
    }
}

// register-light exact fallback (cnt>124, ~never): 33 rescan-extract rounds
__device__ __attribute__((noinline)) void slow_row(const float4* sp, float4 me,
                                                   int row, int lane,
                                                   u16* __restrict__ edge_ws,
                                                   float* __restrict__ dist_ws) {
    u64 thr = 0ull;   // all real keys are > 0 (flip==0 would require NaN dist)
    for (int s = 0; s <= KNN; ++s) {
        u64 best = ~0ull;
        for (int jj = 0; jj < 32; ++jj) {
            int j = jj * 64 + lane;
            u64 x = dist_key(np_dist(me, sp[j]), j);
            if (x > thr && x < best) best = x;
        }
        u32 bh = (u32)(best >> 32);
        u32 rh = wave_min_dpp(bh);
        u32 bl = (bh == rh) ? (u32)best : 0xFFFFFFFFu;
        u32 rl = wave_min_dpp(bl);
        thr = ((u64)rh << 32) | rl;
        if (s >= 1 && lane == s - 1) {
            u32 bb = (rh & 0x80000000u) ? (rh ^ 0x80000000u) : ~rh;
            edge_ws[(size_t)row * KNN + s - 1] = (u16)rl;
            dist_ws[(size_t)row * KNN + s - 1] = __uint_as_float(bb);
        }
    }
}

// one row's pass-2: compact survivors (dist<=pd, float compare) into sl, emit
__device__ __forceinline__ void compact_emit(const float4* sp, float4 me, float pd,
                                             u64* sl, int row, int lane,
                                             u16* __restrict__ edge_ws,
                                             float* __restrict__ dist_ws) {
    u32 base = 0;
#pragma unroll 2
    for (int jj = 0; jj < 32; ++jj) {
        int j = jj * 64 + lane;
        float d = np_dist(me, sp[j]);
        bool s = d <= pd;
        u64 m = __ballot(s);
        u32 pos = base + mbcnt64(m);
        if (s && pos < 128) sl[pos] = ((u64)flip_bits(d) << 32) | (u32)j;
        base += (u32)__popcll(m);
    }
    if ((int)base <= 124) emit_rank(sl, (int)base, row, lane, edge_ws, dist_ws);
    else                  slow_row(sp, me, row, lane, edge_ws, dist_ws);
}

__global__ __launch_bounds__(512, 6) void knn_kernel(const float* __restrict__ pos,
                                                     u16* __restrict__ edge_ws,
                                                     float* __restrict__ dist_ws,
                                                     const float* __restrict__ aw,
                                                     const float* __restrict__ sw,
                                                     float* __restrict__ aw4,
                                                     float* __restrict__ sw4) {
    __shared__ float4 sp[N];          // 32 KB
    __shared__ u64 slots[8][128];     // 8 KB (shared by a wave's two rows)
    const int tid  = threadIdx.x;
    const int lane = tid & 63;
    const int wave = tid >> 6;          // 0..7
    const int rb   = blockIdx.x * 16;   // 16 rows per block, same (b,c)
    const int bc   = rb >> 11;

    const float* posr = pos + (size_t)bc * (N * 3);
    for (int j = tid; j < N; j += 512) {
        float x = posr[3 * j], y = posr[3 * j + 1], z = posr[3 * j + 2];
        sp[j] = make_float4(x, y, z, np_quad(x, y, z));
    }

    // fused prep (block 0 only): repack weights into [f/4][m][f%4]
    if (blockIdx.x == 0) {
#pragma unroll
        for (int it = 0; it < 16; ++it) {
            int i = it * 512 + tid;           // i = f*64 + m
            int f = i >> 6, mm = i & 63;
            int idx = (f >> 2) * 256 + mm * 4 + (f & 3);
            aw4[idx] = aw[mm * 128 + f];
            sw4[idx] = sw[i];
        }
    }
    __syncthreads();

    const int rowA = rb + wave * 2, rowB = rowA + 1;
    const int nA = rowA & (N - 1), nB = nA + 1;
    const float4 meA = sp[nA];
    const float4 meB = sp[nB];

    // ---- pass 1: per-lane float min of dists, both rows ----
    float mnA = __builtin_inff(), mnB = __builtin_inff();
#pragma unroll 8
    for (int jj = 0; jj < 32; ++jj) {
        int j = jj * 64 + lane;
        float4 p = sp[j];
        mnA = fminf(mnA, np_dist(meA, p));
        mnB = fminf(mnB, np_dist(meB, p));
    }

    // ---- pivots: 33rd-smallest lane min (interleaved float bitonic) ----
    float vA = mnA, vB = mnB;
#pragma unroll
    for (int k = 2; k <= 64; k <<= 1) {
#pragma unroll
        for (int j = k >> 1; j > 0; j >>= 1) {
            float oA = __int_as_float(__shfl_xor(__float_as_int(vA), j));
            float oB = __int_as_float(__shfl_xor(__float_as_int(vB), j));
            bool keepmin = (((lane & k) == 0) == ((lane & j) == 0));
            vA = ((oA < vA) == keepmin) ? oA : vA;
            vB = ((oB < vB) == keepmin) ? oB : vB;
        }
    }
    float pdA = __int_as_float(__builtin_amdgcn_readlane(__float_as_int(vA), 32));
    float pdB = __int_as_float(__builtin_amdgcn_readlane(__float_as_int(vB), 32));

    // ---- pass 2: sequential per row, shared slot buffer ----
    compact_emit(sp, meA, pdA, slots[wave], rowA, lane, edge_ws, dist_ws);
    compact_emit(sp, meB, pdB, slots[wave], rowB, lane, edge_ws, dist_ws);
}

// ---------------------------------------------------------------------------
// Kernel 2: angle features + gate + gated aggregation + two 128->64 matvecs.
// One wave per (b,n); 8 consecutive n (same b) per 512-thread block.
// All intermediates wave-private in LDS -> only ONE barrier (outv transpose).
// Phase C: float4 weights from global (VMEM pipe) x float4 theta/h broadcast
// from LDS; unroll 4 to bound in-flight float4 register pressure.
// ---------------------------------------------------------------------------
__global__ __launch_bounds__(512) void conv_kernel(
    const float* __restrict__ pos, const float* __restrict__ node_fea,
    const float* __restrict__ node_mask, const float* __restrict__ aw4,
    const float* __restrict__ sw4, const float* __restrict__ w1,
    const float* __restrict__ w2, const u16* __restrict__ edge_ws,
    const float* __restrict__ dist_ws, float* __restrict__ out) {
    __shared__ __align__(16) float theta_lds[8][128];  // [wave][f], f=kk*4+cc
    __shared__ float gate_lds[8][128];                 // [wave][cc*32+kk]
    __shared__ u16   edge_lds[8][128];                 // [wave][cc*32+kk]
    __shared__ __align__(16) float h_lds[8][128];      // [wave][f], f=cc*32+..
    __shared__ float gsum_lds[8][4];                   // [wave][cc]
    __shared__ float outv[8][65];                      // [n-offset][m], padded

    const int tid  = threadIdx.x;
    const int lane = tid & 63;
    const int wave = tid >> 6;             // 0..7

    const int row0 = blockIdx.x * 8;   // (b,n) row base, same b across block
    const int b    = row0 >> 11;
    const int n0   = row0 & (N - 1);
    const int row  = row0 + wave;
    const int n    = row & (N - 1);
    const float mval = node_mask[b * N + n];

    // gate scalar S = sum_m relu(w1[m]) * w2[m]
    float S = wave_sum_dpp(fmaxf(w1[lane], 0.f) * w2[lane]);

    // ---- Phase A: per (cc,kk) pair: direction, theta, gate (wave-private) ----
#pragma unroll
    for (int it = 0; it < 2; ++it) {
        int p  = it * 64 + lane;
        int cc = p >> 5, kk = p & 31;
        int rowc = (b * C + cc) * N + n;
        int e      = edge_ws[(size_t)rowc * KNN + kk];
        float dist = dist_ws[(size_t)rowc * KNN + kk];
        const float* pp = pos + (size_t)rowc * 3;
        const float* qp = pos + ((size_t)(b * C + cc) * N + e) * 3;
        float dx = qp[0] - pp[0], dy = qp[1] - pp[1], dz = qp[2] - pp[2];
        float nrm = fmaxf(sqrtf(dx * dx + dy * dy + dz * dz), 1e-12f);
        float inv = 1.0f / nrm;
        dx *= inv; dy *= inv; dz *= inv;
        int src = lane & 32;   // lane holding kk==0 for this cc-group
        float n0x = __shfl(dx, src), n0y = __shfl(dy, src), n0z = __shfl(dz, src);
        float cosv = (kk == 0) ? 1.f : (dx * n0x + dy * n0y + dz * n0z);
        theta_lds[wave][kk * 4 + cc] = cosv * mval;

        float g = fmaxf(dist * S, 0.f) * mval;
        float gate = 1.f / (1.f + expf(-g));
        gate_lds[wave][cc * 32 + kk] = gate;
        edge_lds[wave][cc * 32 + kk] = (u16)e;
        float gs = gate;
#pragma unroll
        for (int off = 1; off < 32; off <<= 1) gs += __shfl_xor(gs, off);
        if (kk == 0) gsum_lds[wave][cc] = gs;
    }

    // ---- Phase B: h[f] = sum_k gate * fea_cat (all 64 lanes gather) ----
    {
        int cc = lane >> 4, dd = lane & 15;
        const float* nf = node_fea + (size_t)(b * C + cc) * N * D;
        float own = nf[(size_t)n * D + dd];
        h_lds[wave][cc * 32 + dd] = own * mval * gsum_lds[wave][cc];
        float acc = 0.f;
#pragma unroll
        for (int k = 0; k < 32; ++k) {
            int e = edge_lds[wave][cc * 32 + k];
            acc += gate_lds[wave][cc * 32 + k] * nf[(size_t)e * D + dd];
        }
        h_lds[wave][cc * 32 + 16 + dd] = acc * mval;
    }

    // ---- Phase C: m = lane; two 128->64 matvecs (float4) + epilogue ----
    {
        const float4* wa4 = (const float4*)aw4;
        const float4* wv4 = (const float4*)sw4;
        const float4* th4 = (const float4*)(&theta_lds[wave][0]);
        const float4* hh4 = (const float4*)(&h_lds[wave][0]);
        float fs = 0.f, fe = 0.f;
#pragma unroll 4
        for (int f4 = 0; f4 < 32; ++f4) {
            float4 wa = wa4[f4 * 64 + lane];
            float4 wv = wv4[f4 * 64 + lane];
            float4 tv = th4[f4];
            float4 hv = hh4[f4];
            fs += wa.x * tv.x + wa.y * tv.y + wa.z * tv.z + wa.w * tv.w;
            fe += wv.x * hv.x + wv.y * hv.y + wv.z * hv.z + wv.w * hv.w;
        }
        float v = fs + fe;
        v = (v > 0.f) ? v : 0.01f * v;
        outv[wave][lane] = v * mval;
    }
    __syncthreads();   // the only cross-wave handoff (outv transpose)

    // store: thread t -> m = t>>3, n-offset j = t&7
    {
        int m = tid >> 3, j = tid & 7;
        out[((size_t)(b * 64 + m)) * N + n0 + j] = outv[j][m];
    }
}

// ---------------------------------------------------------------------------
extern "C" void kernel_launch(void* const* d_in, const int* in_sizes, int n_in,
                              void* d_out, int out_size, void* d_ws, size_t ws_size,
                              hipStream_t stream) {
    const float* pos       = (const float*)d_in[0];
    const float* node_fea  = (const float*)d_in[1];
    const float* node_mask = (const float*)d_in[2];
    const float* aw        = (const float*)d_in[3];
    const float* sw        = (const float*)d_in[4];
    const float* w1        = (const float*)d_in[5];
    const float* w2        = (const float*)d_in[6];
    float* out = (float*)d_out;

    // ws: dist f32 4 MB | edge u16 2 MB | aw4 32 KB | sw4 32 KB  (~6.1 MB)
    float* dist_ws = (float*)d_ws;
    u16*   edge_ws = (u16*)((char*)d_ws + 4u * 1024 * 1024);
    float* aw4     = (float*)((char*)d_ws + 6u * 1024 * 1024);
    float* sw4     = (float*)((char*)d_ws + 6u * 1024 * 1024 + 32u * 1024);

    knn_kernel<<<BS * C * N / 16, 512, 0, stream>>>(pos, edge_ws, dist_ws,
                                                    aw, sw, aw4, sw4);
    conv_kernel<<<BS * N / 8, 512, 0, stream>>>(pos, node_fea, node_mask, aw4, sw4,
                                                w1, w2, edge_ws, dist_ws, out);
}